// Round 5
// baseline (243.299 us; speedup 1.0000x reference)
//
#include <hip/hip_runtime.h>
#include <stdint.h>
#include <stddef.h>

#define D_MODEL 1024
#define NHEAD   16
#define DK      64
#define BB      2
#define SS      2048
#define NTOK    (BB*SS)   // 4096

// log2(e) / sqrt(Dk) folded into the Q projection output:
#define SCALE_Q 0.18033688011f

typedef short  short8 __attribute__((ext_vector_type(8)));
typedef __bf16 bf16x8 __attribute__((ext_vector_type(8)));
typedef float  f32x4  __attribute__((ext_vector_type(4)));

__device__ __forceinline__ unsigned short f2bf(float x){   // RNE (cast/gemm path)
  unsigned int u = __builtin_bit_cast(unsigned int, x);
  u += 0x7fffu + ((u >> 16) & 1u);
  return (unsigned short)(u >> 16);
}

// pack two f32 -> two bf16 (round-half-up) in 3 VALU: add, add, v_perm
__device__ __forceinline__ unsigned int pack_bf2(float x, float y){
  unsigned int a = __builtin_bit_cast(unsigned int, x) + 0x8000u;
  unsigned int b = __builtin_bit_cast(unsigned int, y) + 0x8000u;
  return __builtin_amdgcn_perm(b, a, 0x07060302u);  // [y_hi16 | x_hi16]
}

// two f32 -> packed bf16x2 in ONE VALU (RNE). dst.lo = lo, dst.hi = hi.
__device__ __forceinline__ unsigned int cvt_pk_bf16(float lo, float hi){
  unsigned int r;
  asm("v_cvt_pk_bf16_f32 %0, %1, %2" : "=v"(r) : "v"(lo), "v"(hi));
  return r;
}

__device__ __forceinline__ float fast_exp2(float x){
#if __has_builtin(__builtin_amdgcn_exp2f)
  return __builtin_amdgcn_exp2f(x);   // raw v_exp_f32; args bounded, no denorms
#else
  return exp2f(x);
#endif
}

__device__ __forceinline__ f32x4 mfma16(bf16x8 a, bf16x8 b, f32x4 c){
  return __builtin_amdgcn_mfma_f32_16x16x32_bf16(a, b, c, 0, 0, 0);
}

// async global->LDS, 16B/lane; LDS dst = wave-uniform base + lane*16
__device__ __forceinline__ void async16(const void* g, void* lds){
  __builtin_amdgcn_global_load_lds(
      (const __attribute__((address_space(1))) unsigned int*)g,
      (__attribute__((address_space(3))) unsigned int*)lds,
      16, 0, 0);
}

// ---------------------------------------------------------------- cast fp32->bf16
__global__ __launch_bounds__(256) void cast_bf16_all(
    const float* __restrict__ q,  const float* __restrict__ k,  const float* __restrict__ v,
    const float* __restrict__ wq, const float* __restrict__ wk, const float* __restrict__ wv,
    const float* __restrict__ wo,
    unsigned short* __restrict__ qb,  unsigned short* __restrict__ kb,  unsigned short* __restrict__ vb,
    unsigned short* __restrict__ wqb, unsigned short* __restrict__ wkb, unsigned short* __restrict__ wvb,
    unsigned short* __restrict__ wob)
{
  const float* src; unsigned short* dst; int n;
  switch (blockIdx.y){
    case 0: src = q;  dst = qb;  n = NTOK*D_MODEL;    break;
    case 1: src = k;  dst = kb;  n = NTOK*D_MODEL;    break;
    case 2: src = v;  dst = vb;  n = NTOK*D_MODEL;    break;
    case 3: src = wq; dst = wqb; n = D_MODEL*D_MODEL; break;
    case 4: src = wk; dst = wkb; n = D_MODEL*D_MODEL; break;
    case 5: src = wv; dst = wvb; n = D_MODEL*D_MODEL; break;
    default: src = wo; dst = wob; n = D_MODEL*D_MODEL; break;
  }
  int i = (blockIdx.x * 256 + threadIdx.x) * 8;
  if (i >= n) return;
  float4 a = *(const float4*)(src + i);
  float4 b = *(const float4*)(src + i + 4);
  short8 o;
  o[0] = (short)f2bf(a.x); o[1] = (short)f2bf(a.y);
  o[2] = (short)f2bf(a.z); o[3] = (short)f2bf(a.w);
  o[4] = (short)f2bf(b.x); o[5] = (short)f2bf(b.y);
  o[6] = (short)f2bf(b.z); o[7] = (short)f2bf(b.w);
  *(short8*)(dst + i) = o;
}

// ---------------------------------------------------------------- fused QKV NT GEMM
// z=0: Qh = (qb.Wq^T + bq)*SCALE_Q ; z=1: Kh = kb.Wk^T + bk ; z=2: Vt = Wv.vb^T + bv.
// 128x128 tile, BK=64, XOR(row&7) swizzle: conflict-free fragment reads.
__global__ __launch_bounds__(256) void qkv_gemm(
    const unsigned short* __restrict__ qb, const unsigned short* __restrict__ kb,
    const unsigned short* __restrict__ vb,
    const unsigned short* __restrict__ wqb, const unsigned short* __restrict__ wkb,
    const unsigned short* __restrict__ wvb,
    const float* __restrict__ bq, const float* __restrict__ bk, const float* __restrict__ bv,
    unsigned short* __restrict__ Qh, unsigned short* __restrict__ Kh, unsigned short* __restrict__ Vt)
{
  __shared__ __align__(16) unsigned short As[128*64];   // 16 KB
  __shared__ __align__(16) unsigned short Bs[128*64];   // 16 KB
  const int id = blockIdx.x, z = id >> 8, r = id & 255;
  const unsigned short *A, *Bt; const float* bias; unsigned short* C;
  int bm, bn, N, brow; float scale;
  if (z == 0){ A = qb;  Bt = wqb; bias = bq; C = Qh; bm = (r>>3)*128; bn = (r&7)*128; N = 1024; brow = 0; scale = SCALE_Q; }
  else if (z == 1){ A = kb;  Bt = wkb; bias = bk; C = Kh; bm = (r>>3)*128; bn = (r&7)*128; N = 1024; brow = 0; scale = 1.0f; }
  else            { A = wvb; Bt = vb;  bias = bv; C = Vt; bm = (r&7)*128; bn = (r>>3)*128; N = 4096; brow = 1; scale = 1.0f; }
  const int K = 1024;
  const int tid  = threadIdx.x, lane = tid & 63, w = tid >> 6;
  const int quad = lane >> 4,   l16  = lane & 15;
  const int wm = w >> 1, wn = w & 1;
  const int sw = l16 & 7;
  f32x4 acc[4][4] = {};
  for (int kb_ = 0; kb_ < 16; ++kb_){
    const int k0 = kb_ << 6;
    __syncthreads();
    #pragma unroll
    for (int c = 0; c < 4; ++c){
      int chunk = (w*4 + c)*64 + lane;       // 1024 chunks of 16B per tile
      int row = chunk >> 3, c8 = chunk & 7;
      int cs = (c8 ^ (row & 7)) << 3;
      async16(A  + (size_t)(bm + row)*K + k0 + cs, (char*)As + (w*4 + c)*1024);
      async16(Bt + (size_t)(bn + row)*K + k0 + cs, (char*)Bs + (w*4 + c)*1024);
    }
    __syncthreads();
    bf16x8 af[4][2], bf[4][2];
    #pragma unroll
    for (int mt = 0; mt < 4; ++mt)
      #pragma unroll
      for (int ks = 0; ks < 2; ++ks){
        int off = (((ks*4 + quad) ^ sw) << 3);
        af[mt][ks] = *(const bf16x8*)&As[(wm*64 + mt*16 + l16)*64 + off];
        bf[mt][ks] = *(const bf16x8*)&Bs[(wn*64 + mt*16 + l16)*64 + off];
      }
    #pragma unroll
    for (int ks = 0; ks < 2; ++ks)
      #pragma unroll
      for (int mt = 0; mt < 4; ++mt)
        #pragma unroll
        for (int nt = 0; nt < 4; ++nt)
          acc[mt][nt] = mfma16(af[mt][ks], bf[nt][ks], acc[mt][nt]);
  }
  const int m0 = bm + wm*64, n0 = bn + wn*64;
  #pragma unroll
  for (int mt = 0; mt < 4; ++mt){
    #pragma unroll
    for (int nt = 0; nt < 4; ++nt){
      int col = n0 + nt*16 + l16;
      float bc = brow ? 0.0f : bias[col];
      #pragma unroll
      for (int rr = 0; rr < 4; ++rr){
        int row = m0 + mt*16 + quad*4 + rr;
        float val = (acc[mt][nt][rr] + (brow ? bias[row] : bc)) * scale;
        C[(size_t)row*N + col] = f2bf(val);
      }
    }
  }
}

// ---------------------------------------------------------------- out GEMM (fp32)
// 64(M)x128(N) tile, BK=64, grid (8,64)=512 blocks. 4 waves 1x4. 24 KB LDS.
__global__ __launch_bounds__(256) void gemm_out(
    const unsigned short* __restrict__ A, const unsigned short* __restrict__ Bt,
    const float* __restrict__ bias, float* __restrict__ C)
{
  __shared__ __align__(16) unsigned short As[64*64];    // 8 KB
  __shared__ __align__(16) unsigned short Bs[128*64];   // 16 KB
  const int K = 1024, N = 1024;
  const int tid  = threadIdx.x, lane = tid & 63, w = tid >> 6;
  const int quad = lane >> 4,   l16  = lane & 15;
  const int bm = blockIdx.y * 64, bn = blockIdx.x * 128;
  const int sw = l16 & 7;
  f32x4 acc[4][2] = {};
  for (int kb_ = 0; kb_ < 16; ++kb_){
    const int k0 = kb_ << 6;
    __syncthreads();
    #pragma unroll
    for (int c = 0; c < 2; ++c){               // A: 512 chunks, 2/thread
      int chunk = (w*2 + c)*64 + lane;
      int row = chunk >> 3, c8 = chunk & 7;
      async16(A + (size_t)(bm + row)*K + k0 + ((c8 ^ (row & 7)) << 3),
              (char*)As + (w*2 + c)*1024);
    }
    #pragma unroll
    for (int c = 0; c < 4; ++c){               // B: 1024 chunks, 4/thread
      int chunk = (w*4 + c)*64 + lane;
      int row = chunk >> 3, c8 = chunk & 7;
      async16(Bt + (size_t)(bn + row)*K + k0 + ((c8 ^ (row & 7)) << 3),
              (char*)Bs + (w*4 + c)*1024);
    }
    __syncthreads();
    bf16x8 af[4][2], bf[2][2];
    #pragma unroll
    for (int mt = 0; mt < 4; ++mt)
      #pragma unroll
      for (int ks = 0; ks < 2; ++ks)
        af[mt][ks] = *(const bf16x8*)&As[(mt*16 + l16)*64 + (((ks*4 + quad) ^ sw) << 3)];
    #pragma unroll
    for (int nt = 0; nt < 2; ++nt)
      #pragma unroll
      for (int ks = 0; ks < 2; ++ks)
        bf[nt][ks] = *(const bf16x8*)&Bs[(w*32 + nt*16 + l16)*64 + (((ks*4 + quad) ^ sw) << 3)];
    #pragma unroll
    for (int ks = 0; ks < 2; ++ks)
      #pragma unroll
      for (int mt = 0; mt < 4; ++mt)
        #pragma unroll
        for (int nt = 0; nt < 2; ++nt)
          acc[mt][nt] = mfma16(af[mt][ks], bf[nt][ks], acc[mt][nt]);
  }
  #pragma unroll
  for (int mt = 0; mt < 4; ++mt){
    #pragma unroll
    for (int nt = 0; nt < 2; ++nt){
      int col = bn + w*32 + nt*16 + l16;
      float bc = bias[col];
      #pragma unroll
      for (int rr = 0; rr < 4; ++rr){
        int row = bm + mt*16 + quad*4 + rr;
        C[(size_t)row*N + col] = acc[mt][nt][rr] + bc;
      }
    }
  }
}

// ---------------------------------------------------------------- flash attention
// grid (SS/128, B*H), 256 threads = 4 waves x 32 q, r3 geometry (KVBLK=64,
// 48 KB LDS, dbuf). NEW: cross-tile software pipeline (T15 att[2]):
//   iter t: [vmcnt(0); s_barrier; read K(t)+V(t) frags; issue stage(t+1);
//            QK(t) MFMA  ||  softmax(t-1) VALU  ||  PV(t-1) MFMA]
// Softmax/PV of tile t-1 are pure-register (pi-permuted in-reg P from r3), so
// they overlap tile t's LDS-read latency and QK MFMAs. One barrier per iter
// (was 2): tile t-1's LDS reads finished last iter; the barrier separates them
// from stage(t+1) overwriting that buffer. State ping-pongs A/B (static idx).
__global__ __launch_bounds__(256) void attn(
    const unsigned short* __restrict__ Qh, const unsigned short* __restrict__ Kh,
    const unsigned short* __restrict__ Vt, unsigned short* __restrict__ ctx)
{
  __shared__ __align__(16) unsigned short Kbuf[2][64*64];
  __shared__ __align__(16) unsigned short Vbuf[2][64*64];
  __shared__ __align__(16) unsigned short QP[128*64];   // Q tile, then O

  const int tid  = threadIdx.x, lane = tid & 63, w = tid >> 6;
  const int quad = lane >> 4,   l16  = lane & 15;
  const int b = blockIdx.y >> 4, h = blockIdx.y & 15;
  const int q0 = blockIdx.x * 128;
  const int sw = l16 & 7;                    // read-side swizzle key (row&7 == l16&7)
  const int qh = quad >> 1, ql = (quad & 1) * 4;   // V-read decomposition of quad

  // ---- stage Q tile [128 q][64 dk], swizzled
  #pragma unroll
  for (int c = 0; c < 4; ++c){
    int s = (w*4 + c)*64 + lane;
    int row = s >> 3, c8 = s & 7;
    async16(Qh + (size_t)(b*SS + q0 + row)*D_MODEL + h*DK + ((c8 ^ (row & 7)) << 3),
            (char*)QP + (w*4 + c)*1024);
  }

  // per-thread staging sources for K and V (bump by stride each stage)
  const unsigned short* Kp = Kh + (size_t)(b*SS)*D_MODEL + h*DK;
  const unsigned short* Vp = Vt + (size_t)(h*DK)*NTOK + b*SS;
  const unsigned short* ksrc[2];
  const unsigned short* vsrc[2];
  #pragma unroll
  for (int c = 0; c < 2; ++c){
    int s = (w*2 + c)*64 + lane;
    int row = s >> 3, c8 = s & 7;
    int cs = (c8 ^ (row & 7)) << 3;
    ksrc[c] = Kp + (size_t)row*D_MODEL + cs;
    vsrc[c] = Vp + (size_t)row*NTOK  + cs;
  }

  // ---- stage kv tile 0 into buf0
  #pragma unroll
  for (int c = 0; c < 2; ++c){
    async16(ksrc[c], (char*)Kbuf[0] + (w*2 + c)*1024);
    async16(vsrc[c], (char*)Vbuf[0] + (w*2 + c)*1024);
    ksrc[c] += 64*D_MODEL;
    vsrc[c] += 64;
  }
  asm volatile("s_waitcnt vmcnt(0)\n\ts_barrier" ::: "memory");  // Q + tile0 landed

  bf16x8 bq0[2], bq1[2];                     // B-operand = Q rows (n = q)
  #pragma unroll
  for (int ks = 0; ks < 2; ++ks){
    bq0[ks] = *(const bf16x8*)&QP[(w*32 +      l16)*64 + (((ks*4 + quad) ^ sw) << 3)];
    bq1[ks] = *(const bf16x8*)&QP[(w*32 + 16 + l16)*64 + (((ks*4 + quad) ^ sw) << 3)];
  }

  f32x4 acc[2][4] = {};                      // O^T: [qg][dk-tile], col=q, row=dk
  float l0a = 0.0f, l0b = 0.0f, l1a = 0.0f, l1b = 0.0f;

  // --- pipeline stage 1: wait tile, barrier, read K/V frags, stage t+1, QK ---
  auto readstage = [&](int it, f32x4 (&so0)[4], f32x4 (&so1)[4],
                       uint2 (&vfo)[4][2][2]){
    // stage(it) landed (issued one full iter ago); barrier also separates
    // tile it-1's LDS reads (last iter) from stage(it+1) overwriting its buf.
    asm volatile("s_waitcnt vmcnt(0)\n\ts_barrier" ::: "memory");
    const unsigned short* Kc = Kbuf[it & 1];
    const unsigned short* Vc = Vbuf[it & 1];
    bf16x8 kf[4][2];
    #pragma unroll
    for (int mt = 0; mt < 4; ++mt)
      #pragma unroll
      for (int ks = 0; ks < 2; ++ks)
        kf[mt][ks] = *(const bf16x8*)&Kc[(mt*16 + l16)*64 + (((ks*4 + quad) ^ sw) << 3)];
    #pragma unroll
    for (int nt = 0; nt < 4; ++nt)
      #pragma unroll
      for (int ks = 0; ks < 2; ++ks){
        int rb = (nt*16 + l16)*64 + ql;
        vfo[nt][ks][0] = *(const uint2*)&Vc[rb + (((ks*4     + qh) ^ sw) << 3)];
        vfo[nt][ks][1] = *(const uint2*)&Vc[rb + (((ks*4 + 2 + qh) ^ sw) << 3)];
      }
    // prefetch next tile into the other buffer (it=31: garbage, stays in-ws)
    #pragma unroll
    for (int c = 0; c < 2; ++c){
      async16(ksrc[c], (char*)Kbuf[1 - (it & 1)] + (w*2 + c)*1024);
      async16(vsrc[c], (char*)Vbuf[1 - (it & 1)] + (w*2 + c)*1024);
      ksrc[c] += 64*D_MODEL;
      vsrc[c] += 64;
    }
    // S^T = K.Q^T, both qg
    #pragma unroll
    for (int mt = 0; mt < 4; ++mt){
      f32x4 a0 = {}, a1 = {};
      #pragma unroll
      for (int ks = 0; ks < 2; ++ks){
        a0 = mfma16(kf[mt][ks], bq0[ks], a0);
        a1 = mfma16(kf[mt][ks], bq1[ks], a1);
      }
      so0[mt] = a0; so1[mt] = a1;
    }
  };

  // --- pipeline stage 2: softmax + in-reg P + PV (registers only) ---
  auto smpv = [&](f32x4 (&s0)[4], f32x4 (&s1)[4], uint2 (&vfr)[4][2][2]){
    float s0a = 0.0f, s0b = 0.0f, s1a = 0.0f, s1b = 0.0f;
    #pragma unroll
    for (int mt = 0; mt < 4; ++mt)
      #pragma unroll
      for (int rr = 0; rr < 4; ++rr){
        float p0 = fast_exp2(s0[mt][rr]); s0[mt][rr] = p0;
        float p1 = fast_exp2(s1[mt][rr]); s1[mt][rr] = p1;
        if (mt & 1){ s0b += p0; s1b += p1; } else { s0a += p0; s1a += p1; }
      }
    l0a += s0a; l0b += s0b; l1a += s1a; l1b += s1b;
    bf16x8 bp0[2], bp1[2];
    #pragma unroll
    for (int ks = 0; ks < 2; ++ks){
      uint4 t;
      t.x = cvt_pk_bf16(s0[2*ks  ][0], s0[2*ks  ][1]);
      t.y = cvt_pk_bf16(s0[2*ks  ][2], s0[2*ks  ][3]);
      t.z = cvt_pk_bf16(s0[2*ks+1][0], s0[2*ks+1][1]);
      t.w = cvt_pk_bf16(s0[2*ks+1][2], s0[2*ks+1][3]);
      bp0[ks] = __builtin_bit_cast(bf16x8, t);
      t.x = cvt_pk_bf16(s1[2*ks  ][0], s1[2*ks  ][1]);
      t.y = cvt_pk_bf16(s1[2*ks  ][2], s1[2*ks  ][3]);
      t.z = cvt_pk_bf16(s1[2*ks+1][0], s1[2*ks+1][1]);
      t.w = cvt_pk_bf16(s1[2*ks+1][2], s1[2*ks+1][3]);
      bp1[ks] = __builtin_bit_cast(bf16x8, t);
    }
    #pragma unroll
    for (int nt = 0; nt < 4; ++nt)
      #pragma unroll
      for (int ks = 0; ks < 2; ++ks){
        uint4 vv;
        vv.x = vfr[nt][ks][0].x; vv.y = vfr[nt][ks][0].y;
        vv.z = vfr[nt][ks][1].x; vv.w = vfr[nt][ks][1].y;
        bf16x8 vf = __builtin_bit_cast(bf16x8, vv);
        acc[0][nt] = mfma16(vf, bp0[ks], acc[0][nt]);
        acc[1][nt] = mfma16(vf, bp1[ks], acc[1][nt]);
      }
  };

  // A/B ping-pong state (static indexing — no runtime-indexed reg arrays)
  f32x4 sA0[4], sA1[4], sB0[4], sB1[4];
  uint2 vA[4][2][2], vB[4][2][2];

  readstage(0, sA0, sA1, vA);                         // QK(0); stages tile 1
  for (int t = 1; t < 31; t += 2){
    readstage(t,     sB0, sB1, vB);  smpv(sA0, sA1, vA);   // QK(t) || SM/PV(t-1)
    readstage(t + 1, sA0, sA1, vA);  smpv(sB0, sB1, vB);
  }
  readstage(31, sB0, sB1, vB);  smpv(sA0, sA1, vA);
  smpv(sB0, sB1, vB);                                 // drain tile 31

  // ---- epilogue: normalize, O^T -> QP (wave-private), transpose out coalesced
  float l_i[2] = { l0a + l0b, l1a + l1b };
  float inv[2];
  #pragma unroll
  for (int qg = 0; qg < 2; ++qg){
    float t = l_i[qg];
    t += __shfl_xor(t, 16);
    t += __shfl_xor(t, 32);
    inv[qg] = 1.0f / t;
  }
  #pragma unroll
  for (int qg = 0; qg < 2; ++qg){
    int pr = (w*32 + qg*16 + l16)*64;
    #pragma unroll
    for (int nt = 0; nt < 4; ++nt){
      int c8  = nt*2 + (quad >> 1);
      int off = ((c8 ^ sw) << 3) + (quad & 1)*4;
      uint2 p;
      p.x = pack_bf2(acc[qg][nt][0]*inv[qg], acc[qg][nt][1]*inv[qg]);
      p.y = pack_bf2(acc[qg][nt][2]*inv[qg], acc[qg][nt][3]*inv[qg]);
      *(uint2*)&QP[pr + off] = p;
    }
  }
  asm volatile("s_waitcnt lgkmcnt(0)" ::: "memory");
  {
    int r  = w*32 + (lane >> 1);             // wave-private rows: no barrier needed
    int j0 = (lane & 1)*4;
    unsigned short* dst = ctx + (size_t)(b*SS + q0 + r)*D_MODEL + h*DK;
    #pragma unroll
    for (int i = 0; i < 4; ++i){
      int j = j0 + i;
      uint4 d = *(const uint4*)&QP[r*64 + ((j ^ (r & 7)) << 3)];
      *(uint4*)(dst + j*8) = d;
    }
  }
}

// ---------------------------------------------------------------- launch
extern "C" void kernel_launch(void* const* d_in, const int* in_sizes, int n_in,
                              void* d_out, int out_size, void* d_ws, size_t ws_size,
                              hipStream_t stream) {
  const float* q  = (const float*)d_in[0];
  const float* k  = (const float*)d_in[1];
  const float* v  = (const float*)d_in[2];
  const float* Wq = (const float*)d_in[3];
  const float* bq = (const float*)d_in[4];
  const float* Wk = (const float*)d_in[5];
  const float* bk = (const float*)d_in[6];
  const float* Wv = (const float*)d_in[7];
  const float* bv = (const float*)d_in[8];
  const float* Wo = (const float*)d_in[9];
  const float* bo = (const float*)d_in[10];

  char* ws = (char*)d_ws;
  const size_t TOKB = (size_t)NTOK * D_MODEL * 2;     // 8 MB
  const size_t WB   = (size_t)D_MODEL * D_MODEL * 2;  // 2 MB
  unsigned short* qb  = (unsigned short*)ws;             ws += TOKB;
  unsigned short* kb  = (unsigned short*)ws;             ws += TOKB;
  unsigned short* vb  = (unsigned short*)ws;             ws += TOKB;
  unsigned short* wqb = (unsigned short*)ws;             ws += WB;
  unsigned short* wkb = (unsigned short*)ws;             ws += WB;
  unsigned short* wvb = (unsigned short*)ws;             ws += WB;
  unsigned short* wob = (unsigned short*)ws;             ws += WB;
  unsigned short* Qh  = (unsigned short*)ws;             ws += TOKB;  // [4096][1024], pre-scaled
  unsigned short* Kh  = (unsigned short*)ws;             ws += TOKB;  // [4096][1024]
  unsigned short* Vt  = (unsigned short*)ws;             ws += TOKB;  // [1024][4096]
  unsigned short* ctx = (unsigned short*)ws;             ws += TOKB;  // [4096][1024]

  cast_bf16_all<<<dim3(2048, 7), 256, 0, stream>>>(q, k, v, Wq, Wk, Wv, Wo,
                                                   qb, kb, vb, wqb, wkb, wvb, wob);
  qkv_gemm<<<dim3(768), 256, 0, stream>>>(qb, kb, vb, wqb, wkb, wvb,
                                          bq, bk, bv, Qh, Kh, Vt);
  attn<<<dim3(SS/128, BB*NHEAD), 256, 0, stream>>>(Qh, Kh, Vt, ctx);
  gemm_out<<<dim3(8, 64), 256, 0, stream>>>(ctx, wob, bo, (float*)d_out);
}

// Round 6
// 238.320 us; speedup vs baseline: 1.0209x; 1.0209x over previous
//
#include <hip/hip_runtime.h>
#include <stdint.h>
#include <stddef.h>

#define D_MODEL 1024
#define NHEAD   16
#define DK      64
#define BB      2
#define SS      2048
#define NTOK    (BB*SS)   // 4096

// log2(e) / sqrt(Dk) folded into the Q projection output:
#define SCALE_Q 0.18033688011f

typedef short  short8 __attribute__((ext_vector_type(8)));
typedef __bf16 bf16x8 __attribute__((ext_vector_type(8)));
typedef float  f32x4  __attribute__((ext_vector_type(4)));

__device__ __forceinline__ unsigned short f2bf(float x){   // RNE (cast/gemm path)
  unsigned int u = __builtin_bit_cast(unsigned int, x);
  u += 0x7fffu + ((u >> 16) & 1u);
  return (unsigned short)(u >> 16);
}

// pack two f32 -> two bf16 (round-half-up) in 3 VALU: add, add, v_perm
__device__ __forceinline__ unsigned int pack_bf2(float x, float y){
  unsigned int a = __builtin_bit_cast(unsigned int, x) + 0x8000u;
  unsigned int b = __builtin_bit_cast(unsigned int, y) + 0x8000u;
  return __builtin_amdgcn_perm(b, a, 0x07060302u);  // [y_hi16 | x_hi16]
}

// two f32 -> packed bf16x2 in ONE VALU (RNE). dst.lo = lo, dst.hi = hi.
__device__ __forceinline__ unsigned int cvt_pk_bf16(float lo, float hi){
  unsigned int r;
  asm("v_cvt_pk_bf16_f32 %0, %1, %2" : "=v"(r) : "v"(lo), "v"(hi));
  return r;
}

__device__ __forceinline__ float fast_exp2(float x){
#if __has_builtin(__builtin_amdgcn_exp2f)
  return __builtin_amdgcn_exp2f(x);   // raw v_exp_f32; args bounded, no denorms
#else
  return exp2f(x);
#endif
}

__device__ __forceinline__ f32x4 mfma16(bf16x8 a, bf16x8 b, f32x4 c){
  return __builtin_amdgcn_mfma_f32_16x16x32_bf16(a, b, c, 0, 0, 0);
}

// async global->LDS, 16B/lane; LDS dst = wave-uniform base + lane*16
__device__ __forceinline__ void async16(const void* g, void* lds){
  __builtin_amdgcn_global_load_lds(
      (const __attribute__((address_space(1))) unsigned int*)g,
      (__attribute__((address_space(3))) unsigned int*)lds,
      16, 0, 0);
}

// ---------------------------------------------------------------- cast fp32->bf16
__global__ __launch_bounds__(256) void cast_bf16_all(
    const float* __restrict__ q,  const float* __restrict__ k,  const float* __restrict__ v,
    const float* __restrict__ wq, const float* __restrict__ wk, const float* __restrict__ wv,
    const float* __restrict__ wo,
    unsigned short* __restrict__ qb,  unsigned short* __restrict__ kb,  unsigned short* __restrict__ vb,
    unsigned short* __restrict__ wqb, unsigned short* __restrict__ wkb, unsigned short* __restrict__ wvb,
    unsigned short* __restrict__ wob)
{
  const float* src; unsigned short* dst; int n;
  switch (blockIdx.y){
    case 0: src = q;  dst = qb;  n = NTOK*D_MODEL;    break;
    case 1: src = k;  dst = kb;  n = NTOK*D_MODEL;    break;
    case 2: src = v;  dst = vb;  n = NTOK*D_MODEL;    break;
    case 3: src = wq; dst = wqb; n = D_MODEL*D_MODEL; break;
    case 4: src = wk; dst = wkb; n = D_MODEL*D_MODEL; break;
    case 5: src = wv; dst = wvb; n = D_MODEL*D_MODEL; break;
    default: src = wo; dst = wob; n = D_MODEL*D_MODEL; break;
  }
  int i = (blockIdx.x * 256 + threadIdx.x) * 8;
  if (i >= n) return;
  float4 a = *(const float4*)(src + i);
  float4 b = *(const float4*)(src + i + 4);
  short8 o;
  o[0] = (short)f2bf(a.x); o[1] = (short)f2bf(a.y);
  o[2] = (short)f2bf(a.z); o[3] = (short)f2bf(a.w);
  o[4] = (short)f2bf(b.x); o[5] = (short)f2bf(b.y);
  o[6] = (short)f2bf(b.z); o[7] = (short)f2bf(b.w);
  *(short8*)(dst + i) = o;
}

// ---------------------------------------------------------------- fused QKV NT GEMM
// z=0: Qh = (qb.Wq^T + bq)*SCALE_Q ; z=1: Kh = kb.Wk^T + bk ; z=2: Vt = Wv.vb^T + bv.
// 128x128 tile, BK=64, XOR(row&7) swizzle: conflict-free fragment reads.
// NEW (r6): for z=2 the Vt token-column is stored pi32^-1-permuted within each
// 32-token group (pi32inv(z) = 8*((z>>2)&3) + 4*((z>>4)&1) + (z&3)), so attn's
// pi-permuted PV contraction reads V as contiguous b128 fragments.
__global__ __launch_bounds__(256) void qkv_gemm(
    const unsigned short* __restrict__ qb, const unsigned short* __restrict__ kb,
    const unsigned short* __restrict__ vb,
    const unsigned short* __restrict__ wqb, const unsigned short* __restrict__ wkb,
    const unsigned short* __restrict__ wvb,
    const float* __restrict__ bq, const float* __restrict__ bk, const float* __restrict__ bv,
    unsigned short* __restrict__ Qh, unsigned short* __restrict__ Kh, unsigned short* __restrict__ Vt)
{
  __shared__ __align__(16) unsigned short As[128*64];   // 16 KB
  __shared__ __align__(16) unsigned short Bs[128*64];   // 16 KB
  const int id = blockIdx.x, z = id >> 8, r = id & 255;
  const unsigned short *A, *Bt; const float* bias; unsigned short* C;
  int bm, bn, N, brow; float scale;
  if (z == 0){ A = qb;  Bt = wqb; bias = bq; C = Qh; bm = (r>>3)*128; bn = (r&7)*128; N = 1024; brow = 0; scale = SCALE_Q; }
  else if (z == 1){ A = kb;  Bt = wkb; bias = bk; C = Kh; bm = (r>>3)*128; bn = (r&7)*128; N = 1024; brow = 0; scale = 1.0f; }
  else            { A = wvb; Bt = vb;  bias = bv; C = Vt; bm = (r&7)*128; bn = (r>>3)*128; N = 4096; brow = 1; scale = 1.0f; }
  const int K = 1024;
  const int tid  = threadIdx.x, lane = tid & 63, w = tid >> 6;
  const int quad = lane >> 4,   l16  = lane & 15;
  const int wm = w >> 1, wn = w & 1;
  const int sw = l16 & 7;
  f32x4 acc[4][4] = {};
  for (int kb_ = 0; kb_ < 16; ++kb_){
    const int k0 = kb_ << 6;
    __syncthreads();
    #pragma unroll
    for (int c = 0; c < 4; ++c){
      int chunk = (w*4 + c)*64 + lane;       // 1024 chunks of 16B per tile
      int row = chunk >> 3, c8 = chunk & 7;
      int cs = (c8 ^ (row & 7)) << 3;
      async16(A  + (size_t)(bm + row)*K + k0 + cs, (char*)As + (w*4 + c)*1024);
      async16(Bt + (size_t)(bn + row)*K + k0 + cs, (char*)Bs + (w*4 + c)*1024);
    }
    __syncthreads();
    bf16x8 af[4][2], bf[4][2];
    #pragma unroll
    for (int mt = 0; mt < 4; ++mt)
      #pragma unroll
      for (int ks = 0; ks < 2; ++ks){
        int off = (((ks*4 + quad) ^ sw) << 3);
        af[mt][ks] = *(const bf16x8*)&As[(wm*64 + mt*16 + l16)*64 + off];
        bf[mt][ks] = *(const bf16x8*)&Bs[(wn*64 + mt*16 + l16)*64 + off];
      }
    #pragma unroll
    for (int ks = 0; ks < 2; ++ks)
      #pragma unroll
      for (int mt = 0; mt < 4; ++mt)
        #pragma unroll
        for (int nt = 0; nt < 4; ++nt)
          acc[mt][nt] = mfma16(af[mt][ks], bf[nt][ks], acc[mt][nt]);
  }
  const int m0 = bm + wm*64, n0 = bn + wn*64;
  #pragma unroll
  for (int mt = 0; mt < 4; ++mt){
    #pragma unroll
    for (int nt = 0; nt < 4; ++nt){
      int col = n0 + nt*16 + l16;
      // pi32^-1 within the 32-token group: store-col s.t. attn's linear b128
      // fragment read at position x yields V^T[.][pi32(x)] (brow path only).
      int scol = brow ? ((col & ~31) | (((col >> 2) & 3) << 3)
                                    | (((col >> 4) & 1) << 2) | (col & 3))
                      : col;
      float bc = brow ? 0.0f : bias[col];
      #pragma unroll
      for (int rr = 0; rr < 4; ++rr){
        int row = m0 + mt*16 + quad*4 + rr;
        float val = (acc[mt][nt][rr] + (brow ? bias[row] : bc)) * scale;
        C[(size_t)row*N + scol] = f2bf(val);
      }
    }
  }
}

// ---------------------------------------------------------------- out GEMM (fp32)
// 64(M)x128(N) tile, BK=64, grid (8,64)=512 blocks. 4 waves 1x4. 24 KB LDS.
__global__ __launch_bounds__(256) void gemm_out(
    const unsigned short* __restrict__ A, const unsigned short* __restrict__ Bt,
    const float* __restrict__ bias, float* __restrict__ C)
{
  __shared__ __align__(16) unsigned short As[64*64];    // 8 KB
  __shared__ __align__(16) unsigned short Bs[128*64];   // 16 KB
  const int K = 1024, N = 1024;
  const int tid  = threadIdx.x, lane = tid & 63, w = tid >> 6;
  const int quad = lane >> 4,   l16  = lane & 15;
  const int bm = blockIdx.y * 64, bn = blockIdx.x * 128;
  const int sw = l16 & 7;
  f32x4 acc[4][2] = {};
  for (int kb_ = 0; kb_ < 16; ++kb_){
    const int k0 = kb_ << 6;
    __syncthreads();
    #pragma unroll
    for (int c = 0; c < 2; ++c){               // A: 512 chunks, 2/thread
      int chunk = (w*2 + c)*64 + lane;
      int row = chunk >> 3, c8 = chunk & 7;
      async16(A + (size_t)(bm + row)*K + k0 + ((c8 ^ (row & 7)) << 3),
              (char*)As + (w*2 + c)*1024);
    }
    #pragma unroll
    for (int c = 0; c < 4; ++c){               // B: 1024 chunks, 4/thread
      int chunk = (w*4 + c)*64 + lane;
      int row = chunk >> 3, c8 = chunk & 7;
      async16(Bt + (size_t)(bn + row)*K + k0 + ((c8 ^ (row & 7)) << 3),
              (char*)Bs + (w*4 + c)*1024);
    }
    __syncthreads();
    bf16x8 af[4][2], bf[2][2];
    #pragma unroll
    for (int mt = 0; mt < 4; ++mt)
      #pragma unroll
      for (int ks = 0; ks < 2; ++ks)
        af[mt][ks] = *(const bf16x8*)&As[(mt*16 + l16)*64 + (((ks*4 + quad) ^ sw) << 3)];
    #pragma unroll
    for (int nt = 0; nt < 2; ++nt)
      #pragma unroll
      for (int ks = 0; ks < 2; ++ks)
        bf[nt][ks] = *(const bf16x8*)&Bs[(w*32 + nt*16 + l16)*64 + (((ks*4 + quad) ^ sw) << 3)];
    #pragma unroll
    for (int ks = 0; ks < 2; ++ks)
      #pragma unroll
      for (int mt = 0; mt < 4; ++mt)
        #pragma unroll
        for (int nt = 0; nt < 2; ++nt)
          acc[mt][nt] = mfma16(af[mt][ks], bf[nt][ks], acc[mt][nt]);
  }
  #pragma unroll
  for (int mt = 0; mt < 4; ++mt){
    #pragma unroll
    for (int nt = 0; nt < 2; ++nt){
      int col = bn + w*32 + nt*16 + l16;
      float bc = bias[col];
      #pragma unroll
      for (int rr = 0; rr < 4; ++rr){
        int row = bm + mt*16 + quad*4 + rr;
        C[(size_t)row*N + col] = acc[mt][nt][rr] + bc;
      }
    }
  }
}

// ---------------------------------------------------------------- flash attention
// grid (SS/128, B*H), 256 threads = 4 waves x 32 q. r0's proven skeleton
// (KVBLK=64, 48 KB LDS, dbuf staging, vmcnt(4) + raw s_barrier pair) with the
// P LDS ROUND-TRIP ELIMINATED and V read as b128:
//  - PV contraction k-axis permuted by pi on both operands (r3): QK^T output
//    registers ARE the PV B-fragment (v_cvt_pk_bf16_f32, natural order).
//  - Vt global layout is pre-permuted by pi32^-1 (qkv_gemm epilogue), so the
//    V A-fragment is a contiguous, conflict-free ds_read_b128 — same pattern
//    as the K reads (r3's b64 bank penalty is gone).
// Per-wave-iter LDS: 16 b128 (was 20 b128 + 8 b64); no mid-iter lgkmcnt(0).
__global__ __launch_bounds__(256) void attn(
    const unsigned short* __restrict__ Qh, const unsigned short* __restrict__ Kh,
    const unsigned short* __restrict__ Vt, unsigned short* __restrict__ ctx)
{
  __shared__ __align__(16) unsigned short Kbuf[2][64*64];
  __shared__ __align__(16) unsigned short Vbuf[2][64*64];
  __shared__ __align__(16) unsigned short QP[128*64];   // Q tile, then O

  const int tid  = threadIdx.x, lane = tid & 63, w = tid >> 6;
  const int quad = lane >> 4,   l16  = lane & 15;
  const int b = blockIdx.y >> 4, h = blockIdx.y & 15;
  const int q0 = blockIdx.x * 128;
  const int sw = l16 & 7;                    // read-side swizzle key (row&7 == l16&7)

  // ---- stage Q tile [128 q][64 dk], swizzled
  #pragma unroll
  for (int c = 0; c < 4; ++c){
    int s = (w*4 + c)*64 + lane;
    int row = s >> 3, c8 = s & 7;
    async16(Qh + (size_t)(b*SS + q0 + row)*D_MODEL + h*DK + ((c8 ^ (row & 7)) << 3),
            (char*)QP + (w*4 + c)*1024);
  }

  // per-thread staging sources for K and V (bump by stride each stage)
  const unsigned short* Kp = Kh + (size_t)(b*SS)*D_MODEL + h*DK;
  const unsigned short* Vp = Vt + (size_t)(h*DK)*NTOK + b*SS;
  const unsigned short* ksrc[2];
  const unsigned short* vsrc[2];
  #pragma unroll
  for (int c = 0; c < 2; ++c){
    int s = (w*2 + c)*64 + lane;
    int row = s >> 3, c8 = s & 7;
    int cs = (c8 ^ (row & 7)) << 3;
    ksrc[c] = Kp + (size_t)row*D_MODEL + cs;
    vsrc[c] = Vp + (size_t)row*NTOK  + cs;
  }

  // ---- stage kv tile 0 into buf0
  #pragma unroll
  for (int c = 0; c < 2; ++c){
    async16(ksrc[c], (char*)Kbuf[0] + (w*2 + c)*1024);
    async16(vsrc[c], (char*)Vbuf[0] + (w*2 + c)*1024);
    ksrc[c] += 64*D_MODEL;
    vsrc[c] += 64;
  }
  __syncthreads();                           // one-time full drain (Q + tile0)

  bf16x8 bq0[2], bq1[2];                     // B-operand = Q rows (n = q)
  #pragma unroll
  for (int ks = 0; ks < 2; ++ks){
    bq0[ks] = *(const bf16x8*)&QP[(w*32 +      l16)*64 + (((ks*4 + quad) ^ sw) << 3)];
    bq1[ks] = *(const bf16x8*)&QP[(w*32 + 16 + l16)*64 + (((ks*4 + quad) ^ sw) << 3)];
  }

  f32x4 acc[2][4] = {};                      // O^T: [qg][dk-tile], col=q, row=dk
  float l0a = 0.0f, l0b = 0.0f, l1a = 0.0f, l1b = 0.0f;

  for (int it = 0; it < 32; ++it){
    const int cur = it & 1;
    // prefetch next tile into the other buffer (it=31: garbage prefetch, in-ws)
    #pragma unroll
    for (int c = 0; c < 2; ++c){
      async16(ksrc[c], (char*)Kbuf[1 - cur] + (w*2 + c)*1024);
      async16(vsrc[c], (char*)Vbuf[1 - cur] + (w*2 + c)*1024);
      ksrc[c] += 64*D_MODEL;
      vsrc[c] += 64;
    }
    // wait only for CURRENT tile's 4 loads (issued a full compute phase ago);
    // next tile's 4 stay in flight. Raw barrier: no vmcnt(0) drain.
    asm volatile("s_waitcnt vmcnt(4)\n\ts_barrier" ::: "memory");

    const unsigned short* Kc = Kbuf[cur];
    const unsigned short* Vc = Vbuf[cur];

    // K fragments (shared by both qg)
    bf16x8 kf[4][2];
    #pragma unroll
    for (int mt = 0; mt < 4; ++mt)
      #pragma unroll
      for (int ks = 0; ks < 2; ++ks)
        kf[mt][ks] = *(const bf16x8*)&Kc[(mt*16 + l16)*64 + (((ks*4 + quad) ^ sw) << 3)];

    // V fragments: contiguous b128, conflict-free (Vt pre-permuted by pi32^-1
    // in global memory, so position x holds V^T[.][pi(x)]). Hoisted here so
    // LDS latency hides under QK-MFMA + softmax VALU.
    bf16x8 vf[4][2];
    #pragma unroll
    for (int nt = 0; nt < 4; ++nt)
      #pragma unroll
      for (int ks = 0; ks < 2; ++ks)
        vf[nt][ks] = *(const bf16x8*)&Vc[(nt*16 + l16)*64 + (((ks*4 + quad) ^ sw) << 3)];

    // S^T = K.Q^T, both qg flat-interleaved
    f32x4 s0[4] = {}, s1[4] = {};
    #pragma unroll
    for (int mt = 0; mt < 4; ++mt)
      #pragma unroll
      for (int ks = 0; ks < 2; ++ks){
        s0[mt] = mfma16(kf[mt][ks], bq0[ks], s0[mt]);
        s1[mt] = mfma16(kf[mt][ks], bq1[ks], s1[mt]);
      }

    // softmax (no max subtraction) flat across both qg
    float s0a = 0.0f, s0b = 0.0f, s1a = 0.0f, s1b = 0.0f;
    #pragma unroll
    for (int mt = 0; mt < 4; ++mt)
      #pragma unroll
      for (int rr = 0; rr < 4; ++rr){
        float p0 = fast_exp2(s0[mt][rr]); s0[mt][rr] = p0;
        float p1 = fast_exp2(s1[mt][rr]); s1[mt][rr] = p1;
        if (mt & 1){ s0b += p0; s1b += p1; } else { s0a += p0; s1a += p1; }
      }
    l0a += s0a; l0b += s0b; l1a += s1a; l1b += s1b;

    // in-register P -> bf16 B-fragments (natural register order under pi)
    bf16x8 bp0[2], bp1[2];
    #pragma unroll
    for (int ks = 0; ks < 2; ++ks){
      uint4 t;
      t.x = cvt_pk_bf16(s0[2*ks  ][0], s0[2*ks  ][1]);
      t.y = cvt_pk_bf16(s0[2*ks  ][2], s0[2*ks  ][3]);
      t.z = cvt_pk_bf16(s0[2*ks+1][0], s0[2*ks+1][1]);
      t.w = cvt_pk_bf16(s0[2*ks+1][2], s0[2*ks+1][3]);
      bp0[ks] = __builtin_bit_cast(bf16x8, t);
      t.x = cvt_pk_bf16(s1[2*ks  ][0], s1[2*ks  ][1]);
      t.y = cvt_pk_bf16(s1[2*ks  ][2], s1[2*ks  ][3]);
      t.z = cvt_pk_bf16(s1[2*ks+1][0], s1[2*ks+1][1]);
      t.w = cvt_pk_bf16(s1[2*ks+1][2], s1[2*ks+1][3]);
      bp1[ks] = __builtin_bit_cast(bf16x8, t);
    }

    // O^T += V^T.P^T (k-permuted on both sides); qg interleaved
    #pragma unroll
    for (int nt = 0; nt < 4; ++nt)
      #pragma unroll
      for (int ks = 0; ks < 2; ++ks){
        acc[0][nt] = mfma16(vf[nt][ks], bp0[ks], acc[0][nt]);
        acc[1][nt] = mfma16(vf[nt][ks], bp1[ks], acc[1][nt]);
      }

    // all my LDS reads from buf[cur] retired -> safe for others to restage it.
    // Raw barrier: prefetch (vmcnt) stays in flight.
    asm volatile("s_waitcnt lgkmcnt(0)\n\ts_barrier" ::: "memory");
  }

  // ---- epilogue: normalize, O^T -> QP (wave-private), transpose out coalesced
  float l_i[2] = { l0a + l0b, l1a + l1b };
  float inv[2];
  #pragma unroll
  for (int qg = 0; qg < 2; ++qg){
    float t = l_i[qg];
    t += __shfl_xor(t, 16);
    t += __shfl_xor(t, 32);
    inv[qg] = 1.0f / t;
  }
  #pragma unroll
  for (int qg = 0; qg < 2; ++qg){
    int pr = (w*32 + qg*16 + l16)*64;
    #pragma unroll
    for (int nt = 0; nt < 4; ++nt){
      int c8  = nt*2 + (quad >> 1);
      int off = ((c8 ^ sw) << 3) + (quad & 1)*4;
      uint2 p;
      p.x = pack_bf2(acc[qg][nt][0]*inv[qg], acc[qg][nt][1]*inv[qg]);
      p.y = pack_bf2(acc[qg][nt][2]*inv[qg], acc[qg][nt][3]*inv[qg]);
      *(uint2*)&QP[pr + off] = p;
    }
  }
  asm volatile("s_waitcnt lgkmcnt(0)" ::: "memory");
  {
    int r  = w*32 + (lane >> 1);             // wave-private rows: no barrier needed
    int j0 = (lane & 1)*4;
    unsigned short* dst = ctx + (size_t)(b*SS + q0 + r)*D_MODEL + h*DK;
    #pragma unroll
    for (int i = 0; i < 4; ++i){
      int j = j0 + i;
      uint4 d = *(const uint4*)&QP[r*64 + ((j ^ (r & 7)) << 3)];
      *(uint4*)(dst + j*8) = d;
    }
  }
}

// ---------------------------------------------------------------- launch
extern "C" void kernel_launch(void* const* d_in, const int* in_sizes, int n_in,
                              void* d_out, int out_size, void* d_ws, size_t ws_size,
                              hipStream_t stream) {
  const float* q  = (const float*)d_in[0];
  const float* k  = (const float*)d_in[1];
  const float* v  = (const float*)d_in[2];
  const float* Wq = (const float*)d_in[3];
  const float* bq = (const float*)d_in[4];
  const float* Wk = (const float*)d_in[5];
  const float* bk = (const float*)d_in[6];
  const float* Wv = (const float*)d_in[7];
  const float* bv = (const float*)d_in[8];
  const float* Wo = (const float*)d_in[9];
  const float* bo = (const float*)d_in[10];

  char* ws = (char*)d_ws;
  const size_t TOKB = (size_t)NTOK * D_MODEL * 2;     // 8 MB
  const size_t WB   = (size_t)D_MODEL * D_MODEL * 2;  // 2 MB
  unsigned short* qb  = (unsigned short*)ws;             ws += TOKB;
  unsigned short* kb  = (unsigned short*)ws;             ws += TOKB;
  unsigned short* vb  = (unsigned short*)ws;             ws += TOKB;
  unsigned short* wqb = (unsigned short*)ws;             ws += WB;
  unsigned short* wkb = (unsigned short*)ws;             ws += WB;
  unsigned short* wvb = (unsigned short*)ws;             ws += WB;
  unsigned short* wob = (unsigned short*)ws;             ws += WB;
  unsigned short* Qh  = (unsigned short*)ws;             ws += TOKB;  // [4096][1024], pre-scaled
  unsigned short* Kh  = (unsigned short*)ws;             ws += TOKB;  // [4096][1024]
  unsigned short* Vt  = (unsigned short*)ws;             ws += TOKB;  // [1024][4096], pi-permuted cols
  unsigned short* ctx = (unsigned short*)ws;             ws += TOKB;  // [4096][1024]

  cast_bf16_all<<<dim3(2048, 7), 256, 0, stream>>>(q, k, v, Wq, Wk, Wv, Wo,
                                                   qb, kb, vb, wqb, wkb, wvb, wob);
  qkv_gemm<<<dim3(768), 256, 0, stream>>>(qb, kb, vb, wqb, wkb, wvb,
                                          bq, bk, bv, Qh, Kh, Vt);
  attn<<<dim3(SS/128, BB*NHEAD), 256, 0, stream>>>(Qh, Kh, Vt, ctx);
  gemm_out<<<dim3(8, 64), 256, 0, stream>>>(ctx, wob, bo, (float*)d_out);
}

// Round 7
// 232.384 us; speedup vs baseline: 1.0470x; 1.0255x over previous
//
#include <hip/hip_runtime.h>
#include <stdint.h>
#include <stddef.h>

#define D_MODEL 1024
#define NHEAD   16
#define DK      64
#define BB      2
#define SS      2048
#define NTOK    (BB*SS)   // 4096

// log2(e) / sqrt(Dk) folded into the Q projection output:
#define SCALE_Q 0.18033688011f

typedef short  short8 __attribute__((ext_vector_type(8)));
typedef __bf16 bf16x8 __attribute__((ext_vector_type(8)));
typedef float  f32x4  __attribute__((ext_vector_type(4)));

__device__ __forceinline__ unsigned short f2bf(float x){   // RNE (cast path)
  unsigned int u = __builtin_bit_cast(unsigned int, x);
  u += 0x7fffu + ((u >> 16) & 1u);
  return (unsigned short)(u >> 16);
}

// pack two f32 -> two bf16 (round-half-up) in 3 VALU: add, add, v_perm
__device__ __forceinline__ unsigned int pack_bf2(float x, float y){
  unsigned int a = __builtin_bit_cast(unsigned int, x) + 0x8000u;
  unsigned int b = __builtin_bit_cast(unsigned int, y) + 0x8000u;
  return __builtin_amdgcn_perm(b, a, 0x07060302u);  // [y_hi16 | x_hi16]
}

// two f32 -> packed bf16x2 in ONE VALU (RNE). dst.lo = lo, dst.hi = hi.
__device__ __forceinline__ unsigned int cvt_pk_bf16(float lo, float hi){
  unsigned int r;
  asm("v_cvt_pk_bf16_f32 %0, %1, %2" : "=v"(r) : "v"(lo), "v"(hi));
  return r;
}

__device__ __forceinline__ float fast_exp2(float x){
#if __has_builtin(__builtin_amdgcn_exp2f)
  return __builtin_amdgcn_exp2f(x);   // raw v_exp_f32; args bounded, no denorms
#else
  return exp2f(x);
#endif
}

__device__ __forceinline__ f32x4 mfma16(bf16x8 a, bf16x8 b, f32x4 c){
  return __builtin_amdgcn_mfma_f32_16x16x32_bf16(a, b, c, 0, 0, 0);
}

// async global->LDS, 16B/lane; LDS dst = wave-uniform base + lane*16
__device__ __forceinline__ void async16(const void* g, void* lds){
  __builtin_amdgcn_global_load_lds(
      (const __attribute__((address_space(1))) unsigned int*)g,
      (__attribute__((address_space(3))) unsigned int*)lds,
      16, 0, 0);
}

// ---------------------------------------------------------------- cast fp32->bf16
__global__ __launch_bounds__(256) void cast_bf16_all(
    const float* __restrict__ q,  const float* __restrict__ k,  const float* __restrict__ v,
    const float* __restrict__ wq, const float* __restrict__ wk, const float* __restrict__ wv,
    const float* __restrict__ wo,
    unsigned short* __restrict__ qb,  unsigned short* __restrict__ kb,  unsigned short* __restrict__ vb,
    unsigned short* __restrict__ wqb, unsigned short* __restrict__ wkb, unsigned short* __restrict__ wvb,
    unsigned short* __restrict__ wob)
{
  const float* src; unsigned short* dst; int n;
  switch (blockIdx.y){
    case 0: src = q;  dst = qb;  n = NTOK*D_MODEL;    break;
    case 1: src = k;  dst = kb;  n = NTOK*D_MODEL;    break;
    case 2: src = v;  dst = vb;  n = NTOK*D_MODEL;    break;
    case 3: src = wq; dst = wqb; n = D_MODEL*D_MODEL; break;
    case 4: src = wk; dst = wkb; n = D_MODEL*D_MODEL; break;
    case 5: src = wv; dst = wvb; n = D_MODEL*D_MODEL; break;
    default: src = wo; dst = wob; n = D_MODEL*D_MODEL; break;
  }
  int i = (blockIdx.x * 256 + threadIdx.x) * 8;
  if (i >= n) return;
  float4 a = *(const float4*)(src + i);
  float4 b = *(const float4*)(src + i + 4);
  short8 o;
  o[0] = (short)f2bf(a.x); o[1] = (short)f2bf(a.y);
  o[2] = (short)f2bf(a.z); o[3] = (short)f2bf(a.w);
  o[4] = (short)f2bf(b.x); o[5] = (short)f2bf(b.y);
  o[6] = (short)f2bf(b.z); o[7] = (short)f2bf(b.w);
  *(short8*)(dst + i) = o;
}

// ---------------------------------------------------------------- fused QKV NT GEMM
// z=0: Qh = (qb.Wq^T + bq)*SCALE_Q ; z=1: Kh = kb.Wk^T + bk ; z=2: Vt = Wv.vb^T + bv.
// 128x128 tile, BK=64, XOR(row&7) swizzle. r7 epilogue rework:
//  - MFMA operands SWAPPED (mfma(bf,af)): output col=l16=m, rows=n(4quad+rr),
//    so each acc f32x4 holds 4 consecutive n -> packs to 8B.
//  - LDS-transpose epilogue (reuse the 32KB As|Bs buffer): uint2 writes at
//    [m][granule ^ (m&14)] (even key: <=2-way write conflict = free, 16B read
//    pairs stay contiguous), then 8x dwordx4 fully-coalesced global stores.
//  - z=2: the pi32^-1 token permutation (attn's b128-V requirement) folds into
//    the LDS write granule (g -> 2*(g&3)+(g>>2)); maps 4-token runs to 4-token
//    runs, so global stores remain fully coalesced (fixes r6's scol regression).
__global__ __launch_bounds__(256) void qkv_gemm(
    const unsigned short* __restrict__ qb, const unsigned short* __restrict__ kb,
    const unsigned short* __restrict__ vb,
    const unsigned short* __restrict__ wqb, const unsigned short* __restrict__ wkb,
    const unsigned short* __restrict__ wvb,
    const float* __restrict__ bq, const float* __restrict__ bk, const float* __restrict__ bv,
    unsigned short* __restrict__ Qh, unsigned short* __restrict__ Kh, unsigned short* __restrict__ Vt)
{
  __shared__ __align__(16) unsigned short S[128*128];   // 32 KB: As | Bs, reused by epilogue
  unsigned short* As = S;                               // [128 m][64 k]
  unsigned short* Bs = S + 128*64;                      // [128 n][64 k]
  const int id = blockIdx.x, z = id >> 8, r = id & 255;
  const unsigned short *A, *Bt; const float* bias; unsigned short* C;
  int bm, bn, N, brow; float scale;
  if (z == 0){ A = qb;  Bt = wqb; bias = bq; C = Qh; bm = (r>>3)*128; bn = (r&7)*128; N = 1024; brow = 0; scale = SCALE_Q; }
  else if (z == 1){ A = kb;  Bt = wkb; bias = bk; C = Kh; bm = (r>>3)*128; bn = (r&7)*128; N = 1024; brow = 0; scale = 1.0f; }
  else            { A = wvb; Bt = vb;  bias = bv; C = Vt; bm = (r&7)*128; bn = (r>>3)*128; N = 4096; brow = 1; scale = 1.0f; }
  const int K = 1024;
  const int tid  = threadIdx.x, lane = tid & 63, w = tid >> 6;
  const int quad = lane >> 4,   l16  = lane & 15;
  const int wm = w >> 1, wn = w & 1;
  const int sw = l16 & 7;
  f32x4 acc[4][4] = {};
  for (int kb_ = 0; kb_ < 16; ++kb_){
    const int k0 = kb_ << 6;
    __syncthreads();
    #pragma unroll
    for (int c = 0; c < 4; ++c){
      int chunk = (w*4 + c)*64 + lane;       // 1024 chunks of 16B per tile
      int row = chunk >> 3, c8 = chunk & 7;
      int cs = (c8 ^ (row & 7)) << 3;
      async16(A  + (size_t)(bm + row)*K + k0 + cs, (char*)As + (w*4 + c)*1024);
      async16(Bt + (size_t)(bn + row)*K + k0 + cs, (char*)Bs + (w*4 + c)*1024);
    }
    __syncthreads();
    bf16x8 af[4][2], bf[4][2];
    #pragma unroll
    for (int mt = 0; mt < 4; ++mt)
      #pragma unroll
      for (int ks = 0; ks < 2; ++ks){
        int off = (((ks*4 + quad) ^ sw) << 3);
        af[mt][ks] = *(const bf16x8*)&As[(wm*64 + mt*16 + l16)*64 + off];
        bf[mt][ks] = *(const bf16x8*)&Bs[(wn*64 + mt*16 + l16)*64 + off];
      }
    // SWAPPED operand order: col = l16 = m (af tile), rows = n (bf tile).
    #pragma unroll
    for (int ks = 0; ks < 2; ++ks)
      #pragma unroll
      for (int mt = 0; mt < 4; ++mt)
        #pragma unroll
        for (int nt = 0; nt < 4; ++nt)
          acc[mt][nt] = mfma16(bf[nt][ks], af[mt][ks], acc[mt][nt]);
  }

  // ---- epilogue: pack + LDS transpose + coalesced dwordx4 stores
  __syncthreads();                       // all frag reads done; reuse S (32 KB)
  #pragma unroll
  for (int nt = 0; nt < 4; ++nt){
    int nl = wn*64 + nt*16 + 4*quad;     // n base (step 4); rr spans nl..nl+3
    float4 b4;
    if (!brow) b4 = *(const float4*)&bias[bn + nl];
    #pragma unroll
    for (int mt = 0; mt < 4; ++mt){
      int ml = wm*64 + mt*16 + l16;      // m (0..127)
      float bmv = brow ? bias[bm + ml] : 0.0f;
      float v0 = (acc[mt][nt][0] + (brow ? bmv : b4.x)) * scale;
      float v1 = (acc[mt][nt][1] + (brow ? bmv : b4.y)) * scale;
      float v2 = (acc[mt][nt][2] + (brow ? bmv : b4.z)) * scale;
      float v3 = (acc[mt][nt][3] + (brow ? bmv : b4.w)) * scale;
      uint2 p; p.x = pack_bf2(v0, v1); p.y = pack_bf2(v2, v3);
      int gl = nl >> 2;                  // 4-token granule 0..31
      if (brow){                         // fold pi32^-1 (maps 4-runs to 4-runs)
        int g3 = gl & 7;
        gl = (gl & ~7) | ((g3 & 3)*2 + (g3 >> 2));
      }
      int gs = gl ^ (ml & 14);           // even XOR key: write conflicts <=2-way
      *(uint2*)&S[ml*128 + gs*4] = p;
    }
  }
  __syncthreads();
  {
    int rr_ = tid >> 1, hf = tid & 1;    // 2 threads per 128-col row
    size_t rowbase = (size_t)(bm + rr_) * N + bn;
    #pragma unroll
    for (int i = 0; i < 8; ++i){
      int gg = hf*16 + i*2;              // even granule pair
      uint4 d = *(const uint4*)&S[rr_*128 + ((gg ^ (rr_ & 14)) << 2)];
      *(uint4*)&C[rowbase + gg*4] = d;
    }
  }
}

// ---------------------------------------------------------------- out GEMM (fp32)
// 64(M)x128(N) tile, BK=64, grid (8,64)=512 blocks. 4 waves 1x4. 24 KB LDS.
__global__ __launch_bounds__(256) void gemm_out(
    const unsigned short* __restrict__ A, const unsigned short* __restrict__ Bt,
    const float* __restrict__ bias, float* __restrict__ C)
{
  __shared__ __align__(16) unsigned short As[64*64];    // 8 KB
  __shared__ __align__(16) unsigned short Bs[128*64];   // 16 KB
  const int K = 1024, N = 1024;
  const int tid  = threadIdx.x, lane = tid & 63, w = tid >> 6;
  const int quad = lane >> 4,   l16  = lane & 15;
  const int bm = blockIdx.y * 64, bn = blockIdx.x * 128;
  const int sw = l16 & 7;
  f32x4 acc[4][2] = {};
  for (int kb_ = 0; kb_ < 16; ++kb_){
    const int k0 = kb_ << 6;
    __syncthreads();
    #pragma unroll
    for (int c = 0; c < 2; ++c){               // A: 512 chunks, 2/thread
      int chunk = (w*2 + c)*64 + lane;
      int row = chunk >> 3, c8 = chunk & 7;
      async16(A + (size_t)(bm + row)*K + k0 + ((c8 ^ (row & 7)) << 3),
              (char*)As + (w*2 + c)*1024);
    }
    #pragma unroll
    for (int c = 0; c < 4; ++c){               // B: 1024 chunks, 4/thread
      int chunk = (w*4 + c)*64 + lane;
      int row = chunk >> 3, c8 = chunk & 7;
      async16(Bt + (size_t)(bn + row)*K + k0 + ((c8 ^ (row & 7)) << 3),
              (char*)Bs + (w*4 + c)*1024);
    }
    __syncthreads();
    bf16x8 af[4][2], bf[2][2];
    #pragma unroll
    for (int mt = 0; mt < 4; ++mt)
      #pragma unroll
      for (int ks = 0; ks < 2; ++ks)
        af[mt][ks] = *(const bf16x8*)&As[(mt*16 + l16)*64 + (((ks*4 + quad) ^ sw) << 3)];
    #pragma unroll
    for (int nt = 0; nt < 2; ++nt)
      #pragma unroll
      for (int ks = 0; ks < 2; ++ks)
        bf[nt][ks] = *(const bf16x8*)&Bs[(w*32 + nt*16 + l16)*64 + (((ks*4 + quad) ^ sw) << 3)];
    #pragma unroll
    for (int ks = 0; ks < 2; ++ks)
      #pragma unroll
      for (int mt = 0; mt < 4; ++mt)
        #pragma unroll
        for (int nt = 0; nt < 2; ++nt)
          acc[mt][nt] = mfma16(af[mt][ks], bf[nt][ks], acc[mt][nt]);
  }
  #pragma unroll
  for (int mt = 0; mt < 4; ++mt){
    #pragma unroll
    for (int nt = 0; nt < 2; ++nt){
      int col = bn + w*32 + nt*16 + l16;
      float bc = bias[col];
      #pragma unroll
      for (int rr = 0; rr < 4; ++rr){
        int row = bm + mt*16 + quad*4 + rr;
        C[(size_t)row*N + col] = acc[mt][nt][rr] + bc;
      }
    }
  }
}

// ---------------------------------------------------------------- flash attention
// (r6 version, unchanged) grid (SS/128, B*H), 256 threads = 4 waves x 32 q.
// r0 skeleton (KVBLK=64, 48 KB LDS, dbuf, vmcnt(4) + raw s_barrier pair);
// P lives in registers via the pi-permuted PV contraction; V read as
// conflict-free contiguous b128 (Vt global layout pre-permuted by pi32^-1).
__global__ __launch_bounds__(256) void attn(
    const unsigned short* __restrict__ Qh, const unsigned short* __restrict__ Kh,
    const unsigned short* __restrict__ Vt, unsigned short* __restrict__ ctx)
{
  __shared__ __align__(16) unsigned short Kbuf[2][64*64];
  __shared__ __align__(16) unsigned short Vbuf[2][64*64];
  __shared__ __align__(16) unsigned short QP[128*64];   // Q tile, then O

  const int tid  = threadIdx.x, lane = tid & 63, w = tid >> 6;
  const int quad = lane >> 4,   l16  = lane & 15;
  const int b = blockIdx.y >> 4, h = blockIdx.y & 15;
  const int q0 = blockIdx.x * 128;
  const int sw = l16 & 7;                    // read-side swizzle key (row&7 == l16&7)

  // ---- stage Q tile [128 q][64 dk], swizzled
  #pragma unroll
  for (int c = 0; c < 4; ++c){
    int s = (w*4 + c)*64 + lane;
    int row = s >> 3, c8 = s & 7;
    async16(Qh + (size_t)(b*SS + q0 + row)*D_MODEL + h*DK + ((c8 ^ (row & 7)) << 3),
            (char*)QP + (w*4 + c)*1024);
  }

  // per-thread staging sources for K and V (bump by stride each stage)
  const unsigned short* Kp = Kh + (size_t)(b*SS)*D_MODEL + h*DK;
  const unsigned short* Vp = Vt + (size_t)(h*DK)*NTOK + b*SS;
  const unsigned short* ksrc[2];
  const unsigned short* vsrc[2];
  #pragma unroll
  for (int c = 0; c < 2; ++c){
    int s = (w*2 + c)*64 + lane;
    int row = s >> 3, c8 = s & 7;
    int cs = (c8 ^ (row & 7)) << 3;
    ksrc[c] = Kp + (size_t)row*D_MODEL + cs;
    vsrc[c] = Vp + (size_t)row*NTOK  + cs;
  }

  // ---- stage kv tile 0 into buf0
  #pragma unroll
  for (int c = 0; c < 2; ++c){
    async16(ksrc[c], (char*)Kbuf[0] + (w*2 + c)*1024);
    async16(vsrc[c], (char*)Vbuf[0] + (w*2 + c)*1024);
    ksrc[c] += 64*D_MODEL;
    vsrc[c] += 64;
  }
  __syncthreads();                           // one-time full drain (Q + tile0)

  bf16x8 bq0[2], bq1[2];                     // B-operand = Q rows (n = q)
  #pragma unroll
  for (int ks = 0; ks < 2; ++ks){
    bq0[ks] = *(const bf16x8*)&QP[(w*32 +      l16)*64 + (((ks*4 + quad) ^ sw) << 3)];
    bq1[ks] = *(const bf16x8*)&QP[(w*32 + 16 + l16)*64 + (((ks*4 + quad) ^ sw) << 3)];
  }

  f32x4 acc[2][4] = {};                      // O^T: [qg][dk-tile], col=q, row=dk
  float l0a = 0.0f, l0b = 0.0f, l1a = 0.0f, l1b = 0.0f;

  for (int it = 0; it < 32; ++it){
    const int cur = it & 1;
    // prefetch next tile into the other buffer (it=31: garbage prefetch, in-ws)
    #pragma unroll
    for (int c = 0; c < 2; ++c){
      async16(ksrc[c], (char*)Kbuf[1 - cur] + (w*2 + c)*1024);
      async16(vsrc[c], (char*)Vbuf[1 - cur] + (w*2 + c)*1024);
      ksrc[c] += 64*D_MODEL;
      vsrc[c] += 64;
    }
    // wait only for CURRENT tile's 4 loads (issued a full compute phase ago);
    // next tile's 4 stay in flight. Raw barrier: no vmcnt(0) drain.
    asm volatile("s_waitcnt vmcnt(4)\n\ts_barrier" ::: "memory");

    const unsigned short* Kc = Kbuf[cur];
    const unsigned short* Vc = Vbuf[cur];

    // K fragments (shared by both qg)
    bf16x8 kf[4][2];
    #pragma unroll
    for (int mt = 0; mt < 4; ++mt)
      #pragma unroll
      for (int ks = 0; ks < 2; ++ks)
        kf[mt][ks] = *(const bf16x8*)&Kc[(mt*16 + l16)*64 + (((ks*4 + quad) ^ sw) << 3)];

    // V fragments: contiguous b128, conflict-free (Vt pre-permuted by pi32^-1
    // in global memory, so position x holds V^T[.][pi(x)]). Hoisted here so
    // LDS latency hides under QK-MFMA + softmax VALU.
    bf16x8 vf[4][2];
    #pragma unroll
    for (int nt = 0; nt < 4; ++nt)
      #pragma unroll
      for (int ks = 0; ks < 2; ++ks)
        vf[nt][ks] = *(const bf16x8*)&Vc[(nt*16 + l16)*64 + (((ks*4 + quad) ^ sw) << 3)];

    // S^T = K.Q^T, both qg flat-interleaved
    f32x4 s0[4] = {}, s1[4] = {};
    #pragma unroll
    for (int mt = 0; mt < 4; ++mt)
      #pragma unroll
      for (int ks = 0; ks < 2; ++ks){
        s0[mt] = mfma16(kf[mt][ks], bq0[ks], s0[mt]);
        s1[mt] = mfma16(kf[mt][ks], bq1[ks], s1[mt]);
      }

    // softmax (no max subtraction) flat across both qg
    float s0a = 0.0f, s0b = 0.0f, s1a = 0.0f, s1b = 0.0f;
    #pragma unroll
    for (int mt = 0; mt < 4; ++mt)
      #pragma unroll
      for (int rr = 0; rr < 4; ++rr){
        float p0 = fast_exp2(s0[mt][rr]); s0[mt][rr] = p0;
        float p1 = fast_exp2(s1[mt][rr]); s1[mt][rr] = p1;
        if (mt & 1){ s0b += p0; s1b += p1; } else { s0a += p0; s1a += p1; }
      }
    l0a += s0a; l0b += s0b; l1a += s1a; l1b += s1b;

    // in-register P -> bf16 B-fragments (natural register order under pi)
    bf16x8 bp0[2], bp1[2];
    #pragma unroll
    for (int ks = 0; ks < 2; ++ks){
      uint4 t;
      t.x = cvt_pk_bf16(s0[2*ks  ][0], s0[2*ks  ][1]);
      t.y = cvt_pk_bf16(s0[2*ks  ][2], s0[2*ks  ][3]);
      t.z = cvt_pk_bf16(s0[2*ks+1][0], s0[2*ks+1][1]);
      t.w = cvt_pk_bf16(s0[2*ks+1][2], s0[2*ks+1][3]);
      bp0[ks] = __builtin_bit_cast(bf16x8, t);
      t.x = cvt_pk_bf16(s1[2*ks  ][0], s1[2*ks  ][1]);
      t.y = cvt_pk_bf16(s1[2*ks  ][2], s1[2*ks  ][3]);
      t.z = cvt_pk_bf16(s1[2*ks+1][0], s1[2*ks+1][1]);
      t.w = cvt_pk_bf16(s1[2*ks+1][2], s1[2*ks+1][3]);
      bp1[ks] = __builtin_bit_cast(bf16x8, t);
    }

    // O^T += V^T.P^T (k-permuted on both sides); qg interleaved
    #pragma unroll
    for (int nt = 0; nt < 4; ++nt)
      #pragma unroll
      for (int ks = 0; ks < 2; ++ks){
        acc[0][nt] = mfma16(vf[nt][ks], bp0[ks], acc[0][nt]);
        acc[1][nt] = mfma16(vf[nt][ks], bp1[ks], acc[1][nt]);
      }

    // all my LDS reads from buf[cur] retired -> safe for others to restage it.
    // Raw barrier: prefetch (vmcnt) stays in flight.
    asm volatile("s_waitcnt lgkmcnt(0)\n\ts_barrier" ::: "memory");
  }

  // ---- epilogue: normalize, O^T -> QP (wave-private), transpose out coalesced
  float l_i[2] = { l0a + l0b, l1a + l1b };
  float inv[2];
  #pragma unroll
  for (int qg = 0; qg < 2; ++qg){
    float t = l_i[qg];
    t += __shfl_xor(t, 16);
    t += __shfl_xor(t, 32);
    inv[qg] = 1.0f / t;
  }
  #pragma unroll
  for (int qg = 0; qg < 2; ++qg){
    int pr = (w*32 + qg*16 + l16)*64;
    #pragma unroll
    for (int nt = 0; nt < 4; ++nt){
      int c8  = nt*2 + (quad >> 1);
      int off = ((c8 ^ sw) << 3) + (quad & 1)*4;
      uint2 p;
      p.x = pack_bf2(acc[qg][nt][0]*inv[qg], acc[qg][nt][1]*inv[qg]);
      p.y = pack_bf2(acc[qg][nt][2]*inv[qg], acc[qg][nt][3]*inv[qg]);
      *(uint2*)&QP[pr + off] = p;
    }
  }
  asm volatile("s_waitcnt lgkmcnt(0)" ::: "memory");
  {
    int r  = w*32 + (lane >> 1);             // wave-private rows: no barrier needed
    int j0 = (lane & 1)*4;
    unsigned short* dst = ctx + (size_t)(b*SS + q0 + r)*D_MODEL + h*DK;
    #pragma unroll
    for (int i = 0; i < 4; ++i){
      int j = j0 + i;
      uint4 d = *(const uint4*)&QP[r*64 + ((j ^ (r & 7)) << 3)];
      *(uint4*)(dst + j*8) = d;
    }
  }
}

// ---------------------------------------------------------------- launch
extern "C" void kernel_launch(void* const* d_in, const int* in_sizes, int n_in,
                              void* d_out, int out_size, void* d_ws, size_t ws_size,
                              hipStream_t stream) {
  const float* q  = (const float*)d_in[0];
  const float* k  = (const float*)d_in[1];
  const float* v  = (const float*)d_in[2];
  const float* Wq = (const float*)d_in[3];
  const float* bq = (const float*)d_in[4];
  const float* Wk = (const float*)d_in[5];
  const float* bk = (const float*)d_in[6];
  const float* Wv = (const float*)d_in[7];
  const float* bv = (const float*)d_in[8];
  const float* Wo = (const float*)d_in[9];
  const float* bo = (const float*)d_in[10];

  char* ws = (char*)d_ws;
  const size_t TOKB = (size_t)NTOK * D_MODEL * 2;     // 8 MB
  const size_t WB   = (size_t)D_MODEL * D_MODEL * 2;  // 2 MB
  unsigned short* qb  = (unsigned short*)ws;             ws += TOKB;
  unsigned short* kb  = (unsigned short*)ws;             ws += TOKB;
  unsigned short* vb  = (unsigned short*)ws;             ws += TOKB;
  unsigned short* wqb = (unsigned short*)ws;             ws += WB;
  unsigned short* wkb = (unsigned short*)ws;             ws += WB;
  unsigned short* wvb = (unsigned short*)ws;             ws += WB;
  unsigned short* wob = (unsigned short*)ws;             ws += WB;
  unsigned short* Qh  = (unsigned short*)ws;             ws += TOKB;  // [4096][1024], pre-scaled
  unsigned short* Kh  = (unsigned short*)ws;             ws += TOKB;  // [4096][1024]
  unsigned short* Vt  = (unsigned short*)ws;             ws += TOKB;  // [1024][4096], pi-permuted cols
  unsigned short* ctx = (unsigned short*)ws;             ws += TOKB;  // [4096][1024]

  cast_bf16_all<<<dim3(2048, 7), 256, 0, stream>>>(q, k, v, Wq, Wk, Wv, Wo,
                                                   qb, kb, vb, wqb, wkb, wvb, wob);
  qkv_gemm<<<dim3(768), 256, 0, stream>>>(qb, kb, vb, wqb, wkb, wvb,
                                          bq, bk, bv, Qh, Kh, Vt);
  attn<<<dim3(SS/128, BB*NHEAD), 256, 0, stream>>>(Qh, Kh, Vt, ctx);
  gemm_out<<<dim3(8, 64), 256, 0, stream>>>(ctx, wob, bo, (float*)d_out);
}

// Round 8
// 220.449 us; speedup vs baseline: 1.1037x; 1.0541x over previous
//
#include <hip/hip_runtime.h>
#include <stdint.h>
#include <stddef.h>

#define D_MODEL 1024
#define NHEAD   16
#define DK      64
#define BB      2
#define SS      2048
#define NTOK    (BB*SS)   // 4096

// log2(e) / sqrt(Dk) folded into the Q projection output:
#define SCALE_Q 0.18033688011f

typedef short  short8 __attribute__((ext_vector_type(8)));
typedef __bf16 bf16x8 __attribute__((ext_vector_type(8)));
typedef float  f32x4  __attribute__((ext_vector_type(4)));

__device__ __forceinline__ unsigned short f2bf(float x){   // RNE (cast path)
  unsigned int u = __builtin_bit_cast(unsigned int, x);
  u += 0x7fffu + ((u >> 16) & 1u);
  return (unsigned short)(u >> 16);
}

// pack two f32 -> two bf16 (round-half-up) in 3 VALU: add, add, v_perm
__device__ __forceinline__ unsigned int pack_bf2(float x, float y){
  unsigned int a = __builtin_bit_cast(unsigned int, x) + 0x8000u;
  unsigned int b = __builtin_bit_cast(unsigned int, y) + 0x8000u;
  return __builtin_amdgcn_perm(b, a, 0x07060302u);  // [y_hi16 | x_hi16]
}

// two f32 -> packed bf16x2 in ONE VALU (RNE). dst.lo = lo, dst.hi = hi.
__device__ __forceinline__ unsigned int cvt_pk_bf16(float lo, float hi){
  unsigned int r;
  asm("v_cvt_pk_bf16_f32 %0, %1, %2" : "=v"(r) : "v"(lo), "v"(hi));
  return r;
}

__device__ __forceinline__ float fast_exp2(float x){
#if __has_builtin(__builtin_amdgcn_exp2f)
  return __builtin_amdgcn_exp2f(x);   // raw v_exp_f32; args bounded, no denorms
#else
  return exp2f(x);
#endif
}

__device__ __forceinline__ f32x4 mfma16(bf16x8 a, bf16x8 b, f32x4 c){
  return __builtin_amdgcn_mfma_f32_16x16x32_bf16(a, b, c, 0, 0, 0);
}

// async global->LDS, 16B/lane; LDS dst = wave-uniform base + lane*16
__device__ __forceinline__ void async16(const void* g, void* lds){
  __builtin_amdgcn_global_load_lds(
      (const __attribute__((address_space(1))) unsigned int*)g,
      (__attribute__((address_space(3))) unsigned int*)lds,
      16, 0, 0);
}

// ---------------------------------------------------------------- cast fp32->bf16
__global__ __launch_bounds__(256) void cast_bf16_all(
    const float* __restrict__ q,  const float* __restrict__ k,  const float* __restrict__ v,
    const float* __restrict__ wq, const float* __restrict__ wk, const float* __restrict__ wv,
    const float* __restrict__ wo,
    unsigned short* __restrict__ qb,  unsigned short* __restrict__ kb,  unsigned short* __restrict__ vb,
    unsigned short* __restrict__ wqb, unsigned short* __restrict__ wkb, unsigned short* __restrict__ wvb,
    unsigned short* __restrict__ wob)
{
  const float* src; unsigned short* dst; int n;
  switch (blockIdx.y){
    case 0: src = q;  dst = qb;  n = NTOK*D_MODEL;    break;
    case 1: src = k;  dst = kb;  n = NTOK*D_MODEL;    break;
    case 2: src = v;  dst = vb;  n = NTOK*D_MODEL;    break;
    case 3: src = wq; dst = wqb; n = D_MODEL*D_MODEL; break;
    case 4: src = wk; dst = wkb; n = D_MODEL*D_MODEL; break;
    case 5: src = wv; dst = wvb; n = D_MODEL*D_MODEL; break;
    default: src = wo; dst = wob; n = D_MODEL*D_MODEL; break;
  }
  int i = (blockIdx.x * 256 + threadIdx.x) * 8;
  if (i >= n) return;
  float4 a = *(const float4*)(src + i);
  float4 b = *(const float4*)(src + i + 4);
  short8 o;
  o[0] = (short)f2bf(a.x); o[1] = (short)f2bf(a.y);
  o[2] = (short)f2bf(a.z); o[3] = (short)f2bf(a.w);
  o[4] = (short)f2bf(b.x); o[5] = (short)f2bf(b.y);
  o[6] = (short)f2bf(b.z); o[7] = (short)f2bf(b.w);
  *(short8*)(dst + i) = o;
}

// ---------------------------------------------------------------- fused QKV NT GEMM
// z=0: Qh = (qb.Wq^T + bq)*SCALE_Q ; z=1: Kh = kb.Wk^T + bk ; z=2: Vt = Wv.vb^T + bv.
// 128x128 tile. r8 rework: DOUBLE-BUFFERED BK=32 K-loop in the same 32 KB LDS
// (attn's proven skeleton): issue stage(t+1) -> s_waitcnt vmcnt(4) + raw
// s_barrier -> 8 ds_read_b128 -> 16 MFMA -> lgkmcnt(0) + raw s_barrier.
// Staging stays in flight across barriers (no per-step vmcnt(0) drain).
// 32-wide rows use granule key (row>>2)&3: uniform 8 words/bank (b128 floor).
// + bijective XCD swizzle (768%8==0): each XCD runs 96 consecutive tiles of
// one z-slice -> B-panels + active A-panel fit per-XCD L2.
// Epilogue (r7): swapped-operand acc + LDS-transpose + coalesced dwordx4
// stores; z=2 folds the pi32^-1 token permutation into the LDS granule.
__global__ __launch_bounds__(256) void qkv_gemm(
    const unsigned short* __restrict__ qb, const unsigned short* __restrict__ kb,
    const unsigned short* __restrict__ vb,
    const unsigned short* __restrict__ wqb, const unsigned short* __restrict__ wkb,
    const unsigned short* __restrict__ wvb,
    const float* __restrict__ bq, const float* __restrict__ bk, const float* __restrict__ bv,
    unsigned short* __restrict__ Qh, unsigned short* __restrict__ Kh, unsigned short* __restrict__ Vt)
{
  __shared__ __align__(16) unsigned short S[128*128];   // 32 KB total
  unsigned short* As0 = S;                              // [128 m][32 k] 8 KB
  unsigned short* Bs0 = S + 4096;
  unsigned short* As1 = S + 8192;
  unsigned short* Bs1 = S + 12288;

  int bid = blockIdx.x;                                 // XCD swizzle (bijective)
  const int id = (bid & 7) * 96 + (bid >> 3);
  const int z = id >> 8, r = id & 255;
  const unsigned short *A, *Bt; const float* bias; unsigned short* C;
  int bm, bn, N, brow; float scale;
  if (z == 0){ A = qb;  Bt = wqb; bias = bq; C = Qh; bm = (r>>3)*128; bn = (r&7)*128; N = 1024; brow = 0; scale = SCALE_Q; }
  else if (z == 1){ A = kb;  Bt = wkb; bias = bk; C = Kh; bm = (r>>3)*128; bn = (r&7)*128; N = 1024; brow = 0; scale = 1.0f; }
  else            { A = wvb; Bt = vb;  bias = bv; C = Vt; bm = (r&7)*128; bn = (r>>3)*128; N = 4096; brow = 1; scale = 1.0f; }
  const int K = 1024;
  const int tid  = threadIdx.x, lane = tid & 63, w = tid >> 6;
  const int quad = lane >> 4,   l16  = lane & 15;
  const int wm = w >> 1, wn = w & 1;
  const int fsl = (quad ^ ((l16 >> 2) & 3)) << 3;       // fragment-read elem offset

  // per-thread staging sources (BK=32 tile: 512 granules, 2/thread each side)
  const unsigned short* asrc[2];
  const unsigned short* bsrc[2];
  #pragma unroll
  for (int c = 0; c < 2; ++c){
    int s = (w*2 + c)*64 + lane;
    int row = s >> 2, c4 = s & 3;
    int cs = (c4 ^ ((row >> 2) & 3)) << 3;
    asrc[c] = A  + (size_t)(bm + row)*K + cs;
    bsrc[c] = Bt + (size_t)(bn + row)*K + cs;
  }

  // ---- stage k-tile 0 into buf0
  #pragma unroll
  for (int c = 0; c < 2; ++c){
    async16(asrc[c], (char*)As0 + (w*2 + c)*1024);
    async16(bsrc[c], (char*)Bs0 + (w*2 + c)*1024);
    asrc[c] += 32; bsrc[c] += 32;
  }

  f32x4 acc[4][4] = {};
  for (int t = 0; t < 32; ++t){
    const int cur = t & 1;
    unsigned short* An = cur ? As0 : As1;   // next buffer
    unsigned short* Bn = cur ? Bs0 : Bs1;
    #pragma unroll
    for (int c = 0; c < 2; ++c){            // prefetch tile t+1 (t=31: garbage, in-ws)
      async16(asrc[c], (char*)An + (w*2 + c)*1024);
      async16(bsrc[c], (char*)Bn + (w*2 + c)*1024);
      asrc[c] += 32; bsrc[c] += 32;
    }
    // wait only for CURRENT tile's 4 loads; next tile's 4 stay in flight.
    asm volatile("s_waitcnt vmcnt(4)\n\ts_barrier" ::: "memory");

    const unsigned short* Ac = cur ? As1 : As0;
    const unsigned short* Bc = cur ? Bs1 : Bs0;
    bf16x8 af[4], bf[4];
    #pragma unroll
    for (int mt = 0; mt < 4; ++mt){
      af[mt] = *(const bf16x8*)&Ac[(wm*64 + mt*16 + l16)*32 + fsl];
      bf[mt] = *(const bf16x8*)&Bc[(wn*64 + mt*16 + l16)*32 + fsl];
    }
    // SWAPPED operand order: output col = l16 = m, rows = n (4quad+rr).
    #pragma unroll
    for (int mt = 0; mt < 4; ++mt)
      #pragma unroll
      for (int nt = 0; nt < 4; ++nt)
        acc[mt][nt] = mfma16(bf[nt], af[mt], acc[mt][nt]);

    // my frag reads from buf[cur] retired -> safe to restage it next iter.
    asm volatile("s_waitcnt lgkmcnt(0)\n\ts_barrier" ::: "memory");
  }
  // garbage tile-32 DMA may still target As0/Bs0 (= S): drain before reuse.
  asm volatile("s_waitcnt vmcnt(0)\n\ts_barrier" ::: "memory");

  // ---- epilogue: pack + LDS transpose + coalesced dwordx4 stores
  #pragma unroll
  for (int nt = 0; nt < 4; ++nt){
    int nl = wn*64 + nt*16 + 4*quad;     // n base (step 4); rr spans nl..nl+3
    float4 b4;
    if (!brow) b4 = *(const float4*)&bias[bn + nl];
    #pragma unroll
    for (int mt = 0; mt < 4; ++mt){
      int ml = wm*64 + mt*16 + l16;      // m (0..127)
      float bmv = brow ? bias[bm + ml] : 0.0f;
      float v0 = (acc[mt][nt][0] + (brow ? bmv : b4.x)) * scale;
      float v1 = (acc[mt][nt][1] + (brow ? bmv : b4.y)) * scale;
      float v2 = (acc[mt][nt][2] + (brow ? bmv : b4.z)) * scale;
      float v3 = (acc[mt][nt][3] + (brow ? bmv : b4.w)) * scale;
      uint2 p; p.x = pack_bf2(v0, v1); p.y = pack_bf2(v2, v3);
      int gl = nl >> 2;                  // 4-token granule 0..31
      if (brow){                         // fold pi32^-1 (maps 4-runs to 4-runs)
        int g3 = gl & 7;
        gl = (gl & ~7) | ((g3 & 3)*2 + (g3 >> 2));
      }
      int gs = gl ^ (ml & 14);           // even XOR key: write conflicts <=2-way
      *(uint2*)&S[ml*128 + gs*4] = p;
    }
  }
  __syncthreads();
  {
    int rr_ = tid >> 1, hf = tid & 1;    // 2 threads per 128-col row
    size_t rowbase = (size_t)(bm + rr_) * N + bn;
    #pragma unroll
    for (int i = 0; i < 8; ++i){
      int gg = hf*16 + i*2;              // even granule pair
      uint4 d = *(const uint4*)&S[rr_*128 + ((gg ^ (rr_ & 14)) << 2)];
      *(uint4*)&C[rowbase + gg*4] = d;
    }
  }
}

// ---------------------------------------------------------------- out GEMM (fp32)
// 64(M)x128(N) tile, BK=64, grid (8,64)=512 blocks. 4 waves 1x4. 24 KB LDS.
__global__ __launch_bounds__(256) void gemm_out(
    const unsigned short* __restrict__ A, const unsigned short* __restrict__ Bt,
    const float* __restrict__ bias, float* __restrict__ C)
{
  __shared__ __align__(16) unsigned short As[64*64];    // 8 KB
  __shared__ __align__(16) unsigned short Bs[128*64];   // 16 KB
  const int K = 1024, N = 1024;
  const int tid  = threadIdx.x, lane = tid & 63, w = tid >> 6;
  const int quad = lane >> 4,   l16  = lane & 15;
  const int bm = blockIdx.y * 64, bn = blockIdx.x * 128;
  const int sw = l16 & 7;
  f32x4 acc[4][2] = {};
  for (int kb_ = 0; kb_ < 16; ++kb_){
    const int k0 = kb_ << 6;
    __syncthreads();
    #pragma unroll
    for (int c = 0; c < 2; ++c){               // A: 512 chunks, 2/thread
      int chunk = (w*2 + c)*64 + lane;
      int row = chunk >> 3, c8 = chunk & 7;
      async16(A + (size_t)(bm + row)*K + k0 + ((c8 ^ (row & 7)) << 3),
              (char*)As + (w*2 + c)*1024);
    }
    #pragma unroll
    for (int c = 0; c < 4; ++c){               // B: 1024 chunks, 4/thread
      int chunk = (w*4 + c)*64 + lane;
      int row = chunk >> 3, c8 = chunk & 7;
      async16(Bt + (size_t)(bn + row)*K + k0 + ((c8 ^ (row & 7)) << 3),
              (char*)Bs + (w*4 + c)*1024);
    }
    __syncthreads();
    bf16x8 af[4][2], bf[2][2];
    #pragma unroll
    for (int mt = 0; mt < 4; ++mt)
      #pragma unroll
      for (int ks = 0; ks < 2; ++ks)
        af[mt][ks] = *(const bf16x8*)&As[(mt*16 + l16)*64 + (((ks*4 + quad) ^ sw) << 3)];
    #pragma unroll
    for (int nt = 0; nt < 2; ++nt)
      #pragma unroll
      for (int ks = 0; ks < 2; ++ks)
        bf[nt][ks] = *(const bf16x8*)&Bs[(w*32 + nt*16 + l16)*64 + (((ks*4 + quad) ^ sw) << 3)];
    #pragma unroll
    for (int ks = 0; ks < 2; ++ks)
      #pragma unroll
      for (int mt = 0; mt < 4; ++mt)
        #pragma unroll
        for (int nt = 0; nt < 2; ++nt)
          acc[mt][nt] = mfma16(af[mt][ks], bf[nt][ks], acc[mt][nt]);
  }
  #pragma unroll
  for (int mt = 0; mt < 4; ++mt){
    #pragma unroll
    for (int nt = 0; nt < 2; ++nt){
      int col = bn + w*32 + nt*16 + l16;
      float bc = bias[col];
      #pragma unroll
      for (int rr = 0; rr < 4; ++rr){
        int row = bm + mt*16 + quad*4 + rr;
        C[(size_t)row*N + col] = acc[mt][nt][rr] + bc;
      }
    }
  }
}

// ---------------------------------------------------------------- flash attention
// (r6 version, unchanged) grid (SS/128, B*H), 256 threads = 4 waves x 32 q.
// r0 skeleton (KVBLK=64, 48 KB LDS, dbuf, vmcnt(4) + raw s_barrier pair);
// P lives in registers via the pi-permuted PV contraction; V read as
// conflict-free contiguous b128 (Vt global layout pre-permuted by pi32^-1).
__global__ __launch_bounds__(256) void attn(
    const unsigned short* __restrict__ Qh, const unsigned short* __restrict__ Kh,
    const unsigned short* __restrict__ Vt, unsigned short* __restrict__ ctx)
{
  __shared__ __align__(16) unsigned short Kbuf[2][64*64];
  __shared__ __align__(16) unsigned short Vbuf[2][64*64];
  __shared__ __align__(16) unsigned short QP[128*64];   // Q tile, then O

  const int tid  = threadIdx.x, lane = tid & 63, w = tid >> 6;
  const int quad = lane >> 4,   l16  = lane & 15;
  const int b = blockIdx.y >> 4, h = blockIdx.y & 15;
  const int q0 = blockIdx.x * 128;
  const int sw = l16 & 7;                    // read-side swizzle key (row&7 == l16&7)

  // ---- stage Q tile [128 q][64 dk], swizzled
  #pragma unroll
  for (int c = 0; c < 4; ++c){
    int s = (w*4 + c)*64 + lane;
    int row = s >> 3, c8 = s & 7;
    async16(Qh + (size_t)(b*SS + q0 + row)*D_MODEL + h*DK + ((c8 ^ (row & 7)) << 3),
            (char*)QP + (w*4 + c)*1024);
  }

  // per-thread staging sources for K and V (bump by stride each stage)
  const unsigned short* Kp = Kh + (size_t)(b*SS)*D_MODEL + h*DK;
  const unsigned short* Vp = Vt + (size_t)(h*DK)*NTOK + b*SS;
  const unsigned short* ksrc[2];
  const unsigned short* vsrc[2];
  #pragma unroll
  for (int c = 0; c < 2; ++c){
    int s = (w*2 + c)*64 + lane;
    int row = s >> 3, c8 = s & 7;
    int cs = (c8 ^ (row & 7)) << 3;
    ksrc[c] = Kp + (size_t)row*D_MODEL + cs;
    vsrc[c] = Vp + (size_t)row*NTOK  + cs;
  }

  // ---- stage kv tile 0 into buf0
  #pragma unroll
  for (int c = 0; c < 2; ++c){
    async16(ksrc[c], (char*)Kbuf[0] + (w*2 + c)*1024);
    async16(vsrc[c], (char*)Vbuf[0] + (w*2 + c)*1024);
    ksrc[c] += 64*D_MODEL;
    vsrc[c] += 64;
  }
  __syncthreads();                           // one-time full drain (Q + tile0)

  bf16x8 bq0[2], bq1[2];                     // B-operand = Q rows (n = q)
  #pragma unroll
  for (int ks = 0; ks < 2; ++ks){
    bq0[ks] = *(const bf16x8*)&QP[(w*32 +      l16)*64 + (((ks*4 + quad) ^ sw) << 3)];
    bq1[ks] = *(const bf16x8*)&QP[(w*32 + 16 + l16)*64 + (((ks*4 + quad) ^ sw) << 3)];
  }

  f32x4 acc[2][4] = {};                      // O^T: [qg][dk-tile], col=q, row=dk
  float l0a = 0.0f, l0b = 0.0f, l1a = 0.0f, l1b = 0.0f;

  for (int it = 0; it < 32; ++it){
    const int cur = it & 1;
    // prefetch next tile into the other buffer (it=31: garbage prefetch, in-ws)
    #pragma unroll
    for (int c = 0; c < 2; ++c){
      async16(ksrc[c], (char*)Kbuf[1 - cur] + (w*2 + c)*1024);
      async16(vsrc[c], (char*)Vbuf[1 - cur] + (w*2 + c)*1024);
      ksrc[c] += 64*D_MODEL;
      vsrc[c] += 64;
    }
    // wait only for CURRENT tile's 4 loads (issued a full compute phase ago);
    // next tile's 4 stay in flight. Raw barrier: no vmcnt(0) drain.
    asm volatile("s_waitcnt vmcnt(4)\n\ts_barrier" ::: "memory");

    const unsigned short* Kc = Kbuf[cur];
    const unsigned short* Vc = Vbuf[cur];

    // K fragments (shared by both qg)
    bf16x8 kf[4][2];
    #pragma unroll
    for (int mt = 0; mt < 4; ++mt)
      #pragma unroll
      for (int ks = 0; ks < 2; ++ks)
        kf[mt][ks] = *(const bf16x8*)&Kc[(mt*16 + l16)*64 + (((ks*4 + quad) ^ sw) << 3)];

    // V fragments: contiguous b128, conflict-free (Vt pre-permuted by pi32^-1
    // in global memory, so position x holds V^T[.][pi(x)]). Hoisted here so
    // LDS latency hides under QK-MFMA + softmax VALU.
    bf16x8 vf[4][2];
    #pragma unroll
    for (int nt = 0; nt < 4; ++nt)
      #pragma unroll
      for (int ks = 0; ks < 2; ++ks)
        vf[nt][ks] = *(const bf16x8*)&Vc[(nt*16 + l16)*64 + (((ks*4 + quad) ^ sw) << 3)];

    // S^T = K.Q^T, both qg flat-interleaved
    f32x4 s0[4] = {}, s1[4] = {};
    #pragma unroll
    for (int mt = 0; mt < 4; ++mt)
      #pragma unroll
      for (int ks = 0; ks < 2; ++ks){
        s0[mt] = mfma16(kf[mt][ks], bq0[ks], s0[mt]);
        s1[mt] = mfma16(kf[mt][ks], bq1[ks], s1[mt]);
      }

    // softmax (no max subtraction) flat across both qg
    float s0a = 0.0f, s0b = 0.0f, s1a = 0.0f, s1b = 0.0f;
    #pragma unroll
    for (int mt = 0; mt < 4; ++mt)
      #pragma unroll
      for (int rr = 0; rr < 4; ++rr){
        float p0 = fast_exp2(s0[mt][rr]); s0[mt][rr] = p0;
        float p1 = fast_exp2(s1[mt][rr]); s1[mt][rr] = p1;
        if (mt & 1){ s0b += p0; s1b += p1; } else { s0a += p0; s1a += p1; }
      }
    l0a += s0a; l0b += s0b; l1a += s1a; l1b += s1b;

    // in-register P -> bf16 B-fragments (natural register order under pi)
    bf16x8 bp0[2], bp1[2];
    #pragma unroll
    for (int ks = 0; ks < 2; ++ks){
      uint4 t;
      t.x = cvt_pk_bf16(s0[2*ks  ][0], s0[2*ks  ][1]);
      t.y = cvt_pk_bf16(s0[2*ks  ][2], s0[2*ks  ][3]);
      t.z = cvt_pk_bf16(s0[2*ks+1][0], s0[2*ks+1][1]);
      t.w = cvt_pk_bf16(s0[2*ks+1][2], s0[2*ks+1][3]);
      bp0[ks] = __builtin_bit_cast(bf16x8, t);
      t.x = cvt_pk_bf16(s1[2*ks  ][0], s1[2*ks  ][1]);
      t.y = cvt_pk_bf16(s1[2*ks  ][2], s1[2*ks  ][3]);
      t.z = cvt_pk_bf16(s1[2*ks+1][0], s1[2*ks+1][1]);
      t.w = cvt_pk_bf16(s1[2*ks+1][2], s1[2*ks+1][3]);
      bp1[ks] = __builtin_bit_cast(bf16x8, t);
    }

    // O^T += V^T.P^T (k-permuted on both sides); qg interleaved
    #pragma unroll
    for (int nt = 0; nt < 4; ++nt)
      #pragma unroll
      for (int ks = 0; ks < 2; ++ks){
        acc[0][nt] = mfma16(vf[nt][ks], bp0[ks], acc[0][nt]);
        acc[1][nt] = mfma16(vf[nt][ks], bp1[ks], acc[1][nt]);
      }

    // all my LDS reads from buf[cur] retired -> safe for others to restage it.
    // Raw barrier: prefetch (vmcnt) stays in flight.
    asm volatile("s_waitcnt lgkmcnt(0)\n\ts_barrier" ::: "memory");
  }

  // ---- epilogue: normalize, O^T -> QP (wave-private), transpose out coalesced
  float l_i[2] = { l0a + l0b, l1a + l1b };
  float inv[2];
  #pragma unroll
  for (int qg = 0; qg < 2; ++qg){
    float t = l_i[qg];
    t += __shfl_xor(t, 16);
    t += __shfl_xor(t, 32);
    inv[qg] = 1.0f / t;
  }
  #pragma unroll
  for (int qg = 0; qg < 2; ++qg){
    int pr = (w*32 + qg*16 + l16)*64;
    #pragma unroll
    for (int nt = 0; nt < 4; ++nt){
      int c8  = nt*2 + (quad >> 1);
      int off = ((c8 ^ sw) << 3) + (quad & 1)*4;
      uint2 p;
      p.x = pack_bf2(acc[qg][nt][0]*inv[qg], acc[qg][nt][1]*inv[qg]);
      p.y = pack_bf2(acc[qg][nt][2]*inv[qg], acc[qg][nt][3]*inv[qg]);
      *(uint2*)&QP[pr + off] = p;
    }
  }
  asm volatile("s_waitcnt lgkmcnt(0)" ::: "memory");
  {
    int r  = w*32 + (lane >> 1);             // wave-private rows: no barrier needed
    int j0 = (lane & 1)*4;
    unsigned short* dst = ctx + (size_t)(b*SS + q0 + r)*D_MODEL + h*DK;
    #pragma unroll
    for (int i = 0; i < 4; ++i){
      int j = j0 + i;
      uint4 d = *(const uint4*)&QP[r*64 + ((j ^ (r & 7)) << 3)];
      *(uint4*)(dst + j*8) = d;
    }
  }
}

// ---------------------------------------------------------------- launch
extern "C" void kernel_launch(void* const* d_in, const int* in_sizes, int n_in,
                              void* d_out, int out_size, void* d_ws, size_t ws_size,
                              hipStream_t stream) {
  const float* q  = (const float*)d_in[0];
  const float* k  = (const float*)d_in[1];
  const float* v  = (const float*)d_in[2];
  const float* Wq = (const float*)d_in[3];
  const float* bq = (const float*)d_in[4];
  const float* Wk = (const float*)d_in[5];
  const float* bk = (const float*)d_in[6];
  const float* Wv = (const float*)d_in[7];
  const float* bv = (const float*)d_in[8];
  const float* Wo = (const float*)d_in[9];
  const float* bo = (const float*)d_in[10];

  char* ws = (char*)d_ws;
  const size_t TOKB = (size_t)NTOK * D_MODEL * 2;     // 8 MB
  const size_t WB   = (size_t)D_MODEL * D_MODEL * 2;  // 2 MB
  unsigned short* qb  = (unsigned short*)ws;             ws += TOKB;
  unsigned short* kb  = (unsigned short*)ws;             ws += TOKB;
  unsigned short* vb  = (unsigned short*)ws;             ws += TOKB;
  unsigned short* wqb = (unsigned short*)ws;             ws += WB;
  unsigned short* wkb = (unsigned short*)ws;             ws += WB;
  unsigned short* wvb = (unsigned short*)ws;             ws += WB;
  unsigned short* wob = (unsigned short*)ws;             ws += WB;
  unsigned short* Qh  = (unsigned short*)ws;             ws += TOKB;  // [4096][1024], pre-scaled
  unsigned short* Kh  = (unsigned short*)ws;             ws += TOKB;  // [4096][1024]
  unsigned short* Vt  = (unsigned short*)ws;             ws += TOKB;  // [1024][4096], pi-permuted cols
  unsigned short* ctx = (unsigned short*)ws;             ws += TOKB;  // [4096][1024]

  cast_bf16_all<<<dim3(2048, 7), 256, 0, stream>>>(q, k, v, Wq, Wk, Wv, Wo,
                                                   qb, kb, vb, wqb, wkb, wvb, wob);
  qkv_gemm<<<dim3(768), 256, 0, stream>>>(qb, kb, vb, wqb, wkb, wvb,
                                          bq, bk, bv, Qh, Kh, Vt);
  attn<<<dim3(SS/128, BB*NHEAD), 256, 0, stream>>>(Qh, Kh, Vt, ctx);
  gemm_out<<<dim3(8, 64), 256, 0, stream>>>(ctx, wob, bo, (float*)d_out);
}

// Round 9
// 219.961 us; speedup vs baseline: 1.1061x; 1.0022x over previous
//
#include <hip/hip_runtime.h>
#include <stdint.h>
#include <stddef.h>

#define D_MODEL 1024
#define NHEAD   16
#define DK      64
#define BB      2
#define SS      2048
#define NTOK    (BB*SS)   // 4096

// log2(e) / sqrt(Dk) folded into the Q projection output:
#define SCALE_Q 0.18033688011f

typedef short  short8 __attribute__((ext_vector_type(8)));
typedef __bf16 bf16x8 __attribute__((ext_vector_type(8)));
typedef float  f32x4  __attribute__((ext_vector_type(4)));

__device__ __forceinline__ unsigned short f2bf(float x){   // RNE (cast path)
  unsigned int u = __builtin_bit_cast(unsigned int, x);
  u += 0x7fffu + ((u >> 16) & 1u);
  return (unsigned short)(u >> 16);
}

// pack two f32 -> two bf16 (round-half-up) in 3 VALU: add, add, v_perm
__device__ __forceinline__ unsigned int pack_bf2(float x, float y){
  unsigned int a = __builtin_bit_cast(unsigned int, x) + 0x8000u;
  unsigned int b = __builtin_bit_cast(unsigned int, y) + 0x8000u;
  return __builtin_amdgcn_perm(b, a, 0x07060302u);  // [y_hi16 | x_hi16]
}

// two f32 -> packed bf16x2 in ONE VALU (RNE). dst.lo = lo, dst.hi = hi.
__device__ __forceinline__ unsigned int cvt_pk_bf16(float lo, float hi){
  unsigned int r;
  asm("v_cvt_pk_bf16_f32 %0, %1, %2" : "=v"(r) : "v"(lo), "v"(hi));
  return r;
}

__device__ __forceinline__ float fast_exp2(float x){
#if __has_builtin(__builtin_amdgcn_exp2f)
  return __builtin_amdgcn_exp2f(x);   // raw v_exp_f32; args bounded, no denorms
#else
  return exp2f(x);
#endif
}

__device__ __forceinline__ f32x4 mfma16(bf16x8 a, bf16x8 b, f32x4 c){
  return __builtin_amdgcn_mfma_f32_16x16x32_bf16(a, b, c, 0, 0, 0);
}

// async global->LDS, 16B/lane; LDS dst = wave-uniform base + lane*16
__device__ __forceinline__ void async16(const void* g, void* lds){
  __builtin_amdgcn_global_load_lds(
      (const __attribute__((address_space(1))) unsigned int*)g,
      (__attribute__((address_space(3))) unsigned int*)lds,
      16, 0, 0);
}

// ---------------------------------------------------------------- cast fp32->bf16
__global__ __launch_bounds__(256) void cast_bf16_all(
    const float* __restrict__ q,  const float* __restrict__ k,  const float* __restrict__ v,
    const float* __restrict__ wq, const float* __restrict__ wk, const float* __restrict__ wv,
    const float* __restrict__ wo,
    unsigned short* __restrict__ qb,  unsigned short* __restrict__ kb,  unsigned short* __restrict__ vb,
    unsigned short* __restrict__ wqb, unsigned short* __restrict__ wkb, unsigned short* __restrict__ wvb,
    unsigned short* __restrict__ wob)
{
  const float* src; unsigned short* dst; int n;
  switch (blockIdx.y){
    case 0: src = q;  dst = qb;  n = NTOK*D_MODEL;    break;
    case 1: src = k;  dst = kb;  n = NTOK*D_MODEL;    break;
    case 2: src = v;  dst = vb;  n = NTOK*D_MODEL;    break;
    case 3: src = wq; dst = wqb; n = D_MODEL*D_MODEL; break;
    case 4: src = wk; dst = wkb; n = D_MODEL*D_MODEL; break;
    case 5: src = wv; dst = wvb; n = D_MODEL*D_MODEL; break;
    default: src = wo; dst = wob; n = D_MODEL*D_MODEL; break;
  }
  int i = (blockIdx.x * 256 + threadIdx.x) * 8;
  if (i >= n) return;
  float4 a = *(const float4*)(src + i);
  float4 b = *(const float4*)(src + i + 4);
  short8 o;
  o[0] = (short)f2bf(a.x); o[1] = (short)f2bf(a.y);
  o[2] = (short)f2bf(a.z); o[3] = (short)f2bf(a.w);
  o[4] = (short)f2bf(b.x); o[5] = (short)f2bf(b.y);
  o[6] = (short)f2bf(b.z); o[7] = (short)f2bf(b.w);
  *(short8*)(dst + i) = o;
}

// ---------------------------------------------------------------- fused QKV NT GEMM
// (r8 version, unchanged) z=0: Qh=(qb.Wq^T+bq)*SCALE_Q; z=1: Kh=kb.Wk^T+bk;
// z=2: Vt=Wv.vb^T+bv. 128x128 tile, DOUBLE-BUFFERED BK=32 K-loop in 32 KB LDS:
// issue stage(t+1) -> vmcnt(4) + raw s_barrier -> 8 ds_read_b128 -> 16 MFMA ->
// lgkmcnt(0) + raw s_barrier. Bijective XCD swizzle. r7 epilogue (swapped
// operands + LDS transpose + coalesced stores; z=2 folds pi32^-1).
__global__ __launch_bounds__(256) void qkv_gemm(
    const unsigned short* __restrict__ qb, const unsigned short* __restrict__ kb,
    const unsigned short* __restrict__ vb,
    const unsigned short* __restrict__ wqb, const unsigned short* __restrict__ wkb,
    const unsigned short* __restrict__ wvb,
    const float* __restrict__ bq, const float* __restrict__ bk, const float* __restrict__ bv,
    unsigned short* __restrict__ Qh, unsigned short* __restrict__ Kh, unsigned short* __restrict__ Vt)
{
  __shared__ __align__(16) unsigned short S[128*128];   // 32 KB total
  unsigned short* As0 = S;                              // [128 m][32 k] 8 KB
  unsigned short* Bs0 = S + 4096;
  unsigned short* As1 = S + 8192;
  unsigned short* Bs1 = S + 12288;

  int bid = blockIdx.x;                                 // XCD swizzle (bijective)
  const int id = (bid & 7) * 96 + (bid >> 3);
  const int z = id >> 8, r = id & 255;
  const unsigned short *A, *Bt; const float* bias; unsigned short* C;
  int bm, bn, N, brow; float scale;
  if (z == 0){ A = qb;  Bt = wqb; bias = bq; C = Qh; bm = (r>>3)*128; bn = (r&7)*128; N = 1024; brow = 0; scale = SCALE_Q; }
  else if (z == 1){ A = kb;  Bt = wkb; bias = bk; C = Kh; bm = (r>>3)*128; bn = (r&7)*128; N = 1024; brow = 0; scale = 1.0f; }
  else            { A = wvb; Bt = vb;  bias = bv; C = Vt; bm = (r&7)*128; bn = (r>>3)*128; N = 4096; brow = 1; scale = 1.0f; }
  const int K = 1024;
  const int tid  = threadIdx.x, lane = tid & 63, w = tid >> 6;
  const int quad = lane >> 4,   l16  = lane & 15;
  const int wm = w >> 1, wn = w & 1;
  const int fsl = (quad ^ ((l16 >> 2) & 3)) << 3;       // fragment-read elem offset

  // per-thread staging sources (BK=32 tile: 512 granules, 2/thread each side)
  const unsigned short* asrc[2];
  const unsigned short* bsrc[2];
  #pragma unroll
  for (int c = 0; c < 2; ++c){
    int s = (w*2 + c)*64 + lane;
    int row = s >> 2, c4 = s & 3;
    int cs = (c4 ^ ((row >> 2) & 3)) << 3;
    asrc[c] = A  + (size_t)(bm + row)*K + cs;
    bsrc[c] = Bt + (size_t)(bn + row)*K + cs;
  }

  // ---- stage k-tile 0 into buf0
  #pragma unroll
  for (int c = 0; c < 2; ++c){
    async16(asrc[c], (char*)As0 + (w*2 + c)*1024);
    async16(bsrc[c], (char*)Bs0 + (w*2 + c)*1024);
    asrc[c] += 32; bsrc[c] += 32;
  }

  f32x4 acc[4][4] = {};
  for (int t = 0; t < 32; ++t){
    const int cur = t & 1;
    unsigned short* An = cur ? As0 : As1;   // next buffer
    unsigned short* Bn = cur ? Bs0 : Bs1;
    #pragma unroll
    for (int c = 0; c < 2; ++c){            // prefetch tile t+1 (t=31: garbage, in-ws)
      async16(asrc[c], (char*)An + (w*2 + c)*1024);
      async16(bsrc[c], (char*)Bn + (w*2 + c)*1024);
      asrc[c] += 32; bsrc[c] += 32;
    }
    // wait only for CURRENT tile's 4 loads; next tile's 4 stay in flight.
    asm volatile("s_waitcnt vmcnt(4)\n\ts_barrier" ::: "memory");

    const unsigned short* Ac = cur ? As1 : As0;
    const unsigned short* Bc = cur ? Bs1 : Bs0;
    bf16x8 af[4], bf[4];
    #pragma unroll
    for (int mt = 0; mt < 4; ++mt){
      af[mt] = *(const bf16x8*)&Ac[(wm*64 + mt*16 + l16)*32 + fsl];
      bf[mt] = *(const bf16x8*)&Bc[(wn*64 + mt*16 + l16)*32 + fsl];
    }
    // SWAPPED operand order: output col = l16 = m, rows = n (4quad+rr).
    #pragma unroll
    for (int mt = 0; mt < 4; ++mt)
      #pragma unroll
      for (int nt = 0; nt < 4; ++nt)
        acc[mt][nt] = mfma16(bf[nt], af[mt], acc[mt][nt]);

    // my frag reads from buf[cur] retired -> safe to restage it next iter.
    asm volatile("s_waitcnt lgkmcnt(0)\n\ts_barrier" ::: "memory");
  }
  // garbage tile-32 DMA may still target As0/Bs0 (= S): drain before reuse.
  asm volatile("s_waitcnt vmcnt(0)\n\ts_barrier" ::: "memory");

  // ---- epilogue: pack + LDS transpose + coalesced dwordx4 stores
  #pragma unroll
  for (int nt = 0; nt < 4; ++nt){
    int nl = wn*64 + nt*16 + 4*quad;     // n base (step 4); rr spans nl..nl+3
    float4 b4;
    if (!brow) b4 = *(const float4*)&bias[bn + nl];
    #pragma unroll
    for (int mt = 0; mt < 4; ++mt){
      int ml = wm*64 + mt*16 + l16;      // m (0..127)
      float bmv = brow ? bias[bm + ml] : 0.0f;
      float v0 = (acc[mt][nt][0] + (brow ? bmv : b4.x)) * scale;
      float v1 = (acc[mt][nt][1] + (brow ? bmv : b4.y)) * scale;
      float v2 = (acc[mt][nt][2] + (brow ? bmv : b4.z)) * scale;
      float v3 = (acc[mt][nt][3] + (brow ? bmv : b4.w)) * scale;
      uint2 p; p.x = pack_bf2(v0, v1); p.y = pack_bf2(v2, v3);
      int gl = nl >> 2;                  // 4-token granule 0..31
      if (brow){                         // fold pi32^-1 (maps 4-runs to 4-runs)
        int g3 = gl & 7;
        gl = (gl & ~7) | ((g3 & 3)*2 + (g3 >> 2));
      }
      int gs = gl ^ (ml & 14);           // even XOR key: write conflicts <=2-way
      *(uint2*)&S[ml*128 + gs*4] = p;
    }
  }
  __syncthreads();
  {
    int rr_ = tid >> 1, hf = tid & 1;    // 2 threads per 128-col row
    size_t rowbase = (size_t)(bm + rr_) * N + bn;
    #pragma unroll
    for (int i = 0; i < 8; ++i){
      int gg = hf*16 + i*2;              // even granule pair
      uint4 d = *(const uint4*)&S[rr_*128 + ((gg ^ (rr_ & 14)) << 2)];
      *(uint4*)&C[rowbase + gg*4] = d;
    }
  }
}

// ---------------------------------------------------------------- out GEMM (fp32)
// 64(M)x128(N) tile. r9 rework: DOUBLE-BUFFERED BK=64 (48 KB LDS), the proven
// r8 skeleton: issue stage(t+1) [6 loads] -> s_waitcnt vmcnt(6) + raw s_barrier
// -> 12 ds_read_b128 -> 16 MFMA -> lgkmcnt(0) + raw s_barrier. Staging stays
// in flight across barriers (the old per-step __syncthreads drained vmcnt to 0
// and serialized HBM latency into all 16 steps -> 15% MfmaUtil disease).
// + bijective XCD swizzle (512%8==0): each XCD gets 8 consecutive A-row-panels
// x all of B (~3 MB) -> L2-resident. Grid flattened to 1D 512.
// t=15 garbage prefetch reads <=128B past A(=ctx) end: ws has a pad buffer.
__global__ __launch_bounds__(256) void gemm_out(
    const unsigned short* __restrict__ A, const unsigned short* __restrict__ Bt,
    const float* __restrict__ bias, float* __restrict__ C)
{
  __shared__ __align__(16) unsigned short As[2][64*64];    // 8 KB each
  __shared__ __align__(16) unsigned short Bs[2][128*64];   // 16 KB each
  const int K = 1024, N = 1024;
  const int tid  = threadIdx.x, lane = tid & 63, w = tid >> 6;
  const int quad = lane >> 4,   l16  = lane & 15;
  int bid = blockIdx.x;                                    // XCD swizzle (bijective)
  const int id = (bid & 7) * 64 + (bid >> 3);
  const int bm = (id >> 3) * 64, bn = (id & 7) * 128;
  const int sw = l16 & 7;

  // per-thread staging sources (row&7 granule key, as before)
  const unsigned short* asrc[2];
  const unsigned short* bsrc[4];
  #pragma unroll
  for (int c = 0; c < 2; ++c){               // A: 512 chunks, 2/thread
    int chunk = (w*2 + c)*64 + lane;
    int row = chunk >> 3, c8 = chunk & 7;
    asrc[c] = A + (size_t)(bm + row)*K + ((c8 ^ (row & 7)) << 3);
  }
  #pragma unroll
  for (int c = 0; c < 4; ++c){               // B: 1024 chunks, 4/thread
    int chunk = (w*4 + c)*64 + lane;
    int row = chunk >> 3, c8 = chunk & 7;
    bsrc[c] = Bt + (size_t)(bn + row)*K + ((c8 ^ (row & 7)) << 3);
  }

  // ---- stage k-tile 0 into buf0
  #pragma unroll
  for (int c = 0; c < 2; ++c){ async16(asrc[c], (char*)As[0] + (w*2 + c)*1024); asrc[c] += 64; }
  #pragma unroll
  for (int c = 0; c < 4; ++c){ async16(bsrc[c], (char*)Bs[0] + (w*4 + c)*1024); bsrc[c] += 64; }

  f32x4 acc[4][2] = {};
  for (int t = 0; t < 16; ++t){
    const int cur = t & 1;
    #pragma unroll
    for (int c = 0; c < 2; ++c){            // prefetch tile t+1 (t=15: garbage, in pad)
      async16(asrc[c], (char*)As[1 - cur] + (w*2 + c)*1024); asrc[c] += 64;
    }
    #pragma unroll
    for (int c = 0; c < 4; ++c){
      async16(bsrc[c], (char*)Bs[1 - cur] + (w*4 + c)*1024); bsrc[c] += 64;
    }
    // wait only for CURRENT tile's 6 loads; next tile's 6 stay in flight.
    asm volatile("s_waitcnt vmcnt(6)\n\ts_barrier" ::: "memory");

    const unsigned short* Ac = As[cur];
    const unsigned short* Bc = Bs[cur];
    bf16x8 af[4][2], bf[2][2];
    #pragma unroll
    for (int mt = 0; mt < 4; ++mt)
      #pragma unroll
      for (int ks = 0; ks < 2; ++ks)
        af[mt][ks] = *(const bf16x8*)&Ac[(mt*16 + l16)*64 + (((ks*4 + quad) ^ sw) << 3)];
    #pragma unroll
    for (int nt = 0; nt < 2; ++nt)
      #pragma unroll
      for (int ks = 0; ks < 2; ++ks)
        bf[nt][ks] = *(const bf16x8*)&Bs[cur][(w*32 + nt*16 + l16)*64 + (((ks*4 + quad) ^ sw) << 3)];
    #pragma unroll
    for (int ks = 0; ks < 2; ++ks)
      #pragma unroll
      for (int mt = 0; mt < 4; ++mt)
        #pragma unroll
        for (int nt = 0; nt < 2; ++nt)
          acc[mt][nt] = mfma16(af[mt][ks], bf[nt][ks], acc[mt][nt]);

    // my frag reads from buf[cur] retired -> safe to restage it next iter.
    asm volatile("s_waitcnt lgkmcnt(0)\n\ts_barrier" ::: "memory");
  }

  #pragma unroll
  for (int mt = 0; mt < 4; ++mt){
    #pragma unroll
    for (int nt = 0; nt < 2; ++nt){
      int col = bn + w*32 + nt*16 + l16;
      float bc = bias[col];
      #pragma unroll
      for (int rr = 0; rr < 4; ++rr){
        int row = bm + mt*16 + quad*4 + rr;
        C[(size_t)row*N + col] = acc[mt][nt][rr] + bc;
      }
    }
  }
}

// ---------------------------------------------------------------- flash attention
// (r6 version, unchanged) grid (SS/128, B*H), 256 threads = 4 waves x 32 q.
// r0 skeleton (KVBLK=64, 48 KB LDS, dbuf, vmcnt(4) + raw s_barrier pair);
// P lives in registers via the pi-permuted PV contraction; V read as
// conflict-free contiguous b128 (Vt global layout pre-permuted by pi32^-1).
__global__ __launch_bounds__(256) void attn(
    const unsigned short* __restrict__ Qh, const unsigned short* __restrict__ Kh,
    const unsigned short* __restrict__ Vt, unsigned short* __restrict__ ctx)
{
  __shared__ __align__(16) unsigned short Kbuf[2][64*64];
  __shared__ __align__(16) unsigned short Vbuf[2][64*64];
  __shared__ __align__(16) unsigned short QP[128*64];   // Q tile, then O

  const int tid  = threadIdx.x, lane = tid & 63, w = tid >> 6;
  const int quad = lane >> 4,   l16  = lane & 15;
  const int b = blockIdx.y >> 4, h = blockIdx.y & 15;
  const int q0 = blockIdx.x * 128;
  const int sw = l16 & 7;                    // read-side swizzle key (row&7 == l16&7)

  // ---- stage Q tile [128 q][64 dk], swizzled
  #pragma unroll
  for (int c = 0; c < 4; ++c){
    int s = (w*4 + c)*64 + lane;
    int row = s >> 3, c8 = s & 7;
    async16(Qh + (size_t)(b*SS + q0 + row)*D_MODEL + h*DK + ((c8 ^ (row & 7)) << 3),
            (char*)QP + (w*4 + c)*1024);
  }

  // per-thread staging sources for K and V (bump by stride each stage)
  const unsigned short* Kp = Kh + (size_t)(b*SS)*D_MODEL + h*DK;
  const unsigned short* Vp = Vt + (size_t)(h*DK)*NTOK + b*SS;
  const unsigned short* ksrc[2];
  const unsigned short* vsrc[2];
  #pragma unroll
  for (int c = 0; c < 2; ++c){
    int s = (w*2 + c)*64 + lane;
    int row = s >> 3, c8 = s & 7;
    int cs = (c8 ^ (row & 7)) << 3;
    ksrc[c] = Kp + (size_t)row*D_MODEL + cs;
    vsrc[c] = Vp + (size_t)row*NTOK  + cs;
  }

  // ---- stage kv tile 0 into buf0
  #pragma unroll
  for (int c = 0; c < 2; ++c){
    async16(ksrc[c], (char*)Kbuf[0] + (w*2 + c)*1024);
    async16(vsrc[c], (char*)Vbuf[0] + (w*2 + c)*1024);
    ksrc[c] += 64*D_MODEL;
    vsrc[c] += 64;
  }
  __syncthreads();                           // one-time full drain (Q + tile0)

  bf16x8 bq0[2], bq1[2];                     // B-operand = Q rows (n = q)
  #pragma unroll
  for (int ks = 0; ks < 2; ++ks){
    bq0[ks] = *(const bf16x8*)&QP[(w*32 +      l16)*64 + (((ks*4 + quad) ^ sw) << 3)];
    bq1[ks] = *(const bf16x8*)&QP[(w*32 + 16 + l16)*64 + (((ks*4 + quad) ^ sw) << 3)];
  }

  f32x4 acc[2][4] = {};                      // O^T: [qg][dk-tile], col=q, row=dk
  float l0a = 0.0f, l0b = 0.0f, l1a = 0.0f, l1b = 0.0f;

  for (int it = 0; it < 32; ++it){
    const int cur = it & 1;
    // prefetch next tile into the other buffer (it=31: garbage prefetch, in-ws)
    #pragma unroll
    for (int c = 0; c < 2; ++c){
      async16(ksrc[c], (char*)Kbuf[1 - cur] + (w*2 + c)*1024);
      async16(vsrc[c], (char*)Vbuf[1 - cur] + (w*2 + c)*1024);
      ksrc[c] += 64*D_MODEL;
      vsrc[c] += 64;
    }
    // wait only for CURRENT tile's 4 loads (issued a full compute phase ago);
    // next tile's 4 stay in flight. Raw barrier: no vmcnt(0) drain.
    asm volatile("s_waitcnt vmcnt(4)\n\ts_barrier" ::: "memory");

    const unsigned short* Kc = Kbuf[cur];
    const unsigned short* Vc = Vbuf[cur];

    // K fragments (shared by both qg)
    bf16x8 kf[4][2];
    #pragma unroll
    for (int mt = 0; mt < 4; ++mt)
      #pragma unroll
      for (int ks = 0; ks < 2; ++ks)
        kf[mt][ks] = *(const bf16x8*)&Kc[(mt*16 + l16)*64 + (((ks*4 + quad) ^ sw) << 3)];

    // V fragments: contiguous b128, conflict-free (Vt pre-permuted by pi32^-1
    // in global memory, so position x holds V^T[.][pi(x)]). Hoisted here so
    // LDS latency hides under QK-MFMA + softmax VALU.
    bf16x8 vf[4][2];
    #pragma unroll
    for (int nt = 0; nt < 4; ++nt)
      #pragma unroll
      for (int ks = 0; ks < 2; ++ks)
        vf[nt][ks] = *(const bf16x8*)&Vc[(nt*16 + l16)*64 + (((ks*4 + quad) ^ sw) << 3)];

    // S^T = K.Q^T, both qg flat-interleaved
    f32x4 s0[4] = {}, s1[4] = {};
    #pragma unroll
    for (int mt = 0; mt < 4; ++mt)
      #pragma unroll
      for (int ks = 0; ks < 2; ++ks){
        s0[mt] = mfma16(kf[mt][ks], bq0[ks], s0[mt]);
        s1[mt] = mfma16(kf[mt][ks], bq1[ks], s1[mt]);
      }

    // softmax (no max subtraction) flat across both qg
    float s0a = 0.0f, s0b = 0.0f, s1a = 0.0f, s1b = 0.0f;
    #pragma unroll
    for (int mt = 0; mt < 4; ++mt)
      #pragma unroll
      for (int rr = 0; rr < 4; ++rr){
        float p0 = fast_exp2(s0[mt][rr]); s0[mt][rr] = p0;
        float p1 = fast_exp2(s1[mt][rr]); s1[mt][rr] = p1;
        if (mt & 1){ s0b += p0; s1b += p1; } else { s0a += p0; s1a += p1; }
      }
    l0a += s0a; l0b += s0b; l1a += s1a; l1b += s1b;

    // in-register P -> bf16 B-fragments (natural register order under pi)
    bf16x8 bp0[2], bp1[2];
    #pragma unroll
    for (int ks = 0; ks < 2; ++ks){
      uint4 t;
      t.x = cvt_pk_bf16(s0[2*ks  ][0], s0[2*ks  ][1]);
      t.y = cvt_pk_bf16(s0[2*ks  ][2], s0[2*ks  ][3]);
      t.z = cvt_pk_bf16(s0[2*ks+1][0], s0[2*ks+1][1]);
      t.w = cvt_pk_bf16(s0[2*ks+1][2], s0[2*ks+1][3]);
      bp0[ks] = __builtin_bit_cast(bf16x8, t);
      t.x = cvt_pk_bf16(s1[2*ks  ][0], s1[2*ks  ][1]);
      t.y = cvt_pk_bf16(s1[2*ks  ][2], s1[2*ks  ][3]);
      t.z = cvt_pk_bf16(s1[2*ks+1][0], s1[2*ks+1][1]);
      t.w = cvt_pk_bf16(s1[2*ks+1][2], s1[2*ks+1][3]);
      bp1[ks] = __builtin_bit_cast(bf16x8, t);
    }

    // O^T += V^T.P^T (k-permuted on both sides); qg interleaved
    #pragma unroll
    for (int nt = 0; nt < 4; ++nt)
      #pragma unroll
      for (int ks = 0; ks < 2; ++ks){
        acc[0][nt] = mfma16(vf[nt][ks], bp0[ks], acc[0][nt]);
        acc[1][nt] = mfma16(vf[nt][ks], bp1[ks], acc[1][nt]);
      }

    // all my LDS reads from buf[cur] retired -> safe for others to restage it.
    // Raw barrier: prefetch (vmcnt) stays in flight.
    asm volatile("s_waitcnt lgkmcnt(0)\n\ts_barrier" ::: "memory");
  }

  // ---- epilogue: normalize, O^T -> QP (wave-private), transpose out coalesced
  float l_i[2] = { l0a + l0b, l1a + l1b };
  float inv[2];
  #pragma unroll
  for (int qg = 0; qg < 2; ++qg){
    float t = l_i[qg];
    t += __shfl_xor(t, 16);
    t += __shfl_xor(t, 32);
    inv[qg] = 1.0f / t;
  }
  #pragma unroll
  for (int qg = 0; qg < 2; ++qg){
    int pr = (w*32 + qg*16 + l16)*64;
    #pragma unroll
    for (int nt = 0; nt < 4; ++nt){
      int c8  = nt*2 + (quad >> 1);
      int off = ((c8 ^ sw) << 3) + (quad & 1)*4;
      uint2 p;
      p.x = pack_bf2(acc[qg][nt][0]*inv[qg], acc[qg][nt][1]*inv[qg]);
      p.y = pack_bf2(acc[qg][nt][2]*inv[qg], acc[qg][nt][3]*inv[qg]);
      *(uint2*)&QP[pr + off] = p;
    }
  }
  asm volatile("s_waitcnt lgkmcnt(0)" ::: "memory");
  {
    int r  = w*32 + (lane >> 1);             // wave-private rows: no barrier needed
    int j0 = (lane & 1)*4;
    unsigned short* dst = ctx + (size_t)(b*SS + q0 + r)*D_MODEL + h*DK;
    #pragma unroll
    for (int i = 0; i < 4; ++i){
      int j = j0 + i;
      uint4 d = *(const uint4*)&QP[r*64 + ((j ^ (r & 7)) << 3)];
      *(uint4*)(dst + j*8) = d;
    }
  }
}

// ---------------------------------------------------------------- launch
extern "C" void kernel_launch(void* const* d_in, const int* in_sizes, int n_in,
                              void* d_out, int out_size, void* d_ws, size_t ws_size,
                              hipStream_t stream) {
  const float* q  = (const float*)d_in[0];
  const float* k  = (const float*)d_in[1];
  const float* v  = (const float*)d_in[2];
  const float* Wq = (const float*)d_in[3];
  const float* bq = (const float*)d_in[4];
  const float* Wk = (const float*)d_in[5];
  const float* bk = (const float*)d_in[6];
  const float* Wv = (const float*)d_in[7];
  const float* bv = (const float*)d_in[8];
  const float* Wo = (const float*)d_in[9];
  const float* bo = (const float*)d_in[10];

  char* ws = (char*)d_ws;
  const size_t TOKB = (size_t)NTOK * D_MODEL * 2;     // 8 MB
  const size_t WB   = (size_t)D_MODEL * D_MODEL * 2;  // 2 MB
  unsigned short* qb  = (unsigned short*)ws;             ws += TOKB;
  unsigned short* kb  = (unsigned short*)ws;             ws += TOKB;
  unsigned short* vb  = (unsigned short*)ws;             ws += TOKB;
  unsigned short* wqb = (unsigned short*)ws;             ws += WB;
  unsigned short* wkb = (unsigned short*)ws;             ws += WB;
  unsigned short* wvb = (unsigned short*)ws;             ws += WB;
  unsigned short* wob = (unsigned short*)ws;             ws += WB;
  unsigned short* Qh  = (unsigned short*)ws;             ws += TOKB;  // [4096][1024], pre-scaled
  unsigned short* Kh  = (unsigned short*)ws;             ws += TOKB;  // [4096][1024]
  unsigned short* Vt  = (unsigned short*)ws;             ws += TOKB;  // [1024][4096], pi-permuted cols
  unsigned short* ctx = (unsigned short*)ws;             ws += TOKB;  // [4096][1024]
  ws += 4096;   // pad: gemm_out's t=15 garbage prefetch reads <=128B past ctx

  cast_bf16_all<<<dim3(2048, 7), 256, 0, stream>>>(q, k, v, Wq, Wk, Wv, Wo,
                                                   qb, kb, vb, wqb, wkb, wvb, wob);
  qkv_gemm<<<dim3(768), 256, 0, stream>>>(qb, kb, vb, wqb, wkb, wvb,
                                          bq, bk, bv, Qh, Kh, Vt);
  attn<<<dim3(SS/128, BB*NHEAD), 256, 0, stream>>>(Qh, Kh, Vt, ctx);
  gemm_out<<<dim3(512), 256, 0, stream>>>(ctx, wob, bo, (float*)d_out);
}

// Round 10
// 212.689 us; speedup vs baseline: 1.1439x; 1.0342x over previous
//
#include <hip/hip_runtime.h>
#include <stdint.h>
#include <stddef.h>

#define D_MODEL 1024
#define NHEAD   16
#define DK      64
#define BB      2
#define SS      2048
#define NTOK    (BB*SS)   // 4096

// log2(e) / sqrt(Dk) folded into the Q projection output:
#define SCALE_Q 0.18033688011f

typedef short  short8 __attribute__((ext_vector_type(8)));
typedef __bf16 bf16x8 __attribute__((ext_vector_type(8)));
typedef float  f32x4  __attribute__((ext_vector_type(4)));

__device__ __forceinline__ unsigned short f2bf(float x){   // RNE (cast path)
  unsigned int u = __builtin_bit_cast(unsigned int, x);
  u += 0x7fffu + ((u >> 16) & 1u);
  return (unsigned short)(u >> 16);
}

// pack two f32 -> two bf16 (round-half-up) in 3 VALU: add, add, v_perm
__device__ __forceinline__ unsigned int pack_bf2(float x, float y){
  unsigned int a = __builtin_bit_cast(unsigned int, x) + 0x8000u;
  unsigned int b = __builtin_bit_cast(unsigned int, y) + 0x8000u;
  return __builtin_amdgcn_perm(b, a, 0x07060302u);  // [y_hi16 | x_hi16]
}

// two f32 -> packed bf16x2 in ONE VALU (RNE). dst.lo = lo, dst.hi = hi.
__device__ __forceinline__ unsigned int cvt_pk_bf16(float lo, float hi){
  unsigned int r;
  asm("v_cvt_pk_bf16_f32 %0, %1, %2" : "=v"(r) : "v"(lo), "v"(hi));
  return r;
}

__device__ __forceinline__ float fast_exp2(float x){
#if __has_builtin(__builtin_amdgcn_exp2f)
  return __builtin_amdgcn_exp2f(x);   // raw v_exp_f32; args bounded, no denorms
#else
  return exp2f(x);
#endif
}

__device__ __forceinline__ f32x4 mfma16(bf16x8 a, bf16x8 b, f32x4 c){
  return __builtin_amdgcn_mfma_f32_16x16x32_bf16(a, b, c, 0, 0, 0);
}

// async global->LDS, 16B/lane; LDS dst = wave-uniform base + lane*16
__device__ __forceinline__ void async16(const void* g, void* lds){
  __builtin_amdgcn_global_load_lds(
      (const __attribute__((address_space(1))) unsigned int*)g,
      (__attribute__((address_space(3))) unsigned int*)lds,
      16, 0, 0);
}

// ---------------------------------------------------------------- cast fp32->bf16
__global__ __launch_bounds__(256) void cast_bf16_all(
    const float* __restrict__ q,  const float* __restrict__ k,  const float* __restrict__ v,
    const float* __restrict__ wq, const float* __restrict__ wk, const float* __restrict__ wv,
    const float* __restrict__ wo,
    unsigned short* __restrict__ qb,  unsigned short* __restrict__ kb,  unsigned short* __restrict__ vb,
    unsigned short* __restrict__ wqb, unsigned short* __restrict__ wkb, unsigned short* __restrict__ wvb,
    unsigned short* __restrict__ wob)
{
  const float* src; unsigned short* dst; int n;
  switch (blockIdx.y){
    case 0: src = q;  dst = qb;  n = NTOK*D_MODEL;    break;
    case 1: src = k;  dst = kb;  n = NTOK*D_MODEL;    break;
    case 2: src = v;  dst = vb;  n = NTOK*D_MODEL;    break;
    case 3: src = wq; dst = wqb; n = D_MODEL*D_MODEL; break;
    case 4: src = wk; dst = wkb; n = D_MODEL*D_MODEL; break;
    case 5: src = wv; dst = wvb; n = D_MODEL*D_MODEL; break;
    default: src = wo; dst = wob; n = D_MODEL*D_MODEL; break;
  }
  int i = (blockIdx.x * 256 + threadIdx.x) * 8;
  if (i >= n) return;
  float4 a = *(const float4*)(src + i);
  float4 b = *(const float4*)(src + i + 4);
  short8 o;
  o[0] = (short)f2bf(a.x); o[1] = (short)f2bf(a.y);
  o[2] = (short)f2bf(a.z); o[3] = (short)f2bf(a.w);
  o[4] = (short)f2bf(b.x); o[5] = (short)f2bf(b.y);
  o[6] = (short)f2bf(b.z); o[7] = (short)f2bf(b.w);
  *(short8*)(dst + i) = o;
}

// ---------------------------------------------------------------- fused QKV NT GEMM
// (r8 version, unchanged) z=0: Qh=(qb.Wq^T+bq)*SCALE_Q; z=1: Kh=kb.Wk^T+bk;
// z=2: Vt=Wv.vb^T+bv. 128x128 tile, DOUBLE-BUFFERED BK=32 K-loop in 32 KB LDS:
// issue stage(t+1) -> vmcnt(4) + raw s_barrier -> 8 ds_read_b128 -> 16 MFMA ->
// lgkmcnt(0) + raw s_barrier. Bijective XCD swizzle. r7 epilogue (swapped
// operands + LDS transpose + coalesced stores; z=2 folds pi32^-1).
__global__ __launch_bounds__(256) void qkv_gemm(
    const unsigned short* __restrict__ qb, const unsigned short* __restrict__ kb,
    const unsigned short* __restrict__ vb,
    const unsigned short* __restrict__ wqb, const unsigned short* __restrict__ wkb,
    const unsigned short* __restrict__ wvb,
    const float* __restrict__ bq, const float* __restrict__ bk, const float* __restrict__ bv,
    unsigned short* __restrict__ Qh, unsigned short* __restrict__ Kh, unsigned short* __restrict__ Vt)
{
  __shared__ __align__(16) unsigned short S[128*128];   // 32 KB total
  unsigned short* As0 = S;                              // [128 m][32 k] 8 KB
  unsigned short* Bs0 = S + 4096;
  unsigned short* As1 = S + 8192;
  unsigned short* Bs1 = S + 12288;

  int bid = blockIdx.x;                                 // XCD swizzle (bijective)
  const int id = (bid & 7) * 96 + (bid >> 3);
  const int z = id >> 8, r = id & 255;
  const unsigned short *A, *Bt; const float* bias; unsigned short* C;
  int bm, bn, N, brow; float scale;
  if (z == 0){ A = qb;  Bt = wqb; bias = bq; C = Qh; bm = (r>>3)*128; bn = (r&7)*128; N = 1024; brow = 0; scale = SCALE_Q; }
  else if (z == 1){ A = kb;  Bt = wkb; bias = bk; C = Kh; bm = (r>>3)*128; bn = (r&7)*128; N = 1024; brow = 0; scale = 1.0f; }
  else            { A = wvb; Bt = vb;  bias = bv; C = Vt; bm = (r&7)*128; bn = (r>>3)*128; N = 4096; brow = 1; scale = 1.0f; }
  const int K = 1024;
  const int tid  = threadIdx.x, lane = tid & 63, w = tid >> 6;
  const int quad = lane >> 4,   l16  = lane & 15;
  const int wm = w >> 1, wn = w & 1;
  const int fsl = (quad ^ ((l16 >> 2) & 3)) << 3;       // fragment-read elem offset

  // per-thread staging sources (BK=32 tile: 512 granules, 2/thread each side)
  const unsigned short* asrc[2];
  const unsigned short* bsrc[2];
  #pragma unroll
  for (int c = 0; c < 2; ++c){
    int s = (w*2 + c)*64 + lane;
    int row = s >> 2, c4 = s & 3;
    int cs = (c4 ^ ((row >> 2) & 3)) << 3;
    asrc[c] = A  + (size_t)(bm + row)*K + cs;
    bsrc[c] = Bt + (size_t)(bn + row)*K + cs;
  }

  // ---- stage k-tile 0 into buf0
  #pragma unroll
  for (int c = 0; c < 2; ++c){
    async16(asrc[c], (char*)As0 + (w*2 + c)*1024);
    async16(bsrc[c], (char*)Bs0 + (w*2 + c)*1024);
    asrc[c] += 32; bsrc[c] += 32;
  }

  f32x4 acc[4][4] = {};
  for (int t = 0; t < 32; ++t){
    const int cur = t & 1;
    unsigned short* An = cur ? As0 : As1;   // next buffer
    unsigned short* Bn = cur ? Bs0 : Bs1;
    #pragma unroll
    for (int c = 0; c < 2; ++c){            // prefetch tile t+1 (t=31: garbage, in-ws)
      async16(asrc[c], (char*)An + (w*2 + c)*1024);
      async16(bsrc[c], (char*)Bn + (w*2 + c)*1024);
      asrc[c] += 32; bsrc[c] += 32;
    }
    // wait only for CURRENT tile's 4 loads; next tile's 4 stay in flight.
    asm volatile("s_waitcnt vmcnt(4)\n\ts_barrier" ::: "memory");

    const unsigned short* Ac = cur ? As1 : As0;
    const unsigned short* Bc = cur ? Bs1 : Bs0;
    bf16x8 af[4], bf[4];
    #pragma unroll
    for (int mt = 0; mt < 4; ++mt){
      af[mt] = *(const bf16x8*)&Ac[(wm*64 + mt*16 + l16)*32 + fsl];
      bf[mt] = *(const bf16x8*)&Bc[(wn*64 + mt*16 + l16)*32 + fsl];
    }
    // SWAPPED operand order: output col = l16 = m, rows = n (4quad+rr).
    #pragma unroll
    for (int mt = 0; mt < 4; ++mt)
      #pragma unroll
      for (int nt = 0; nt < 4; ++nt)
        acc[mt][nt] = mfma16(bf[nt], af[mt], acc[mt][nt]);

    // my frag reads from buf[cur] retired -> safe to restage it next iter.
    asm volatile("s_waitcnt lgkmcnt(0)\n\ts_barrier" ::: "memory");
  }
  // garbage tile-32 DMA may still target As0/Bs0 (= S): drain before reuse.
  asm volatile("s_waitcnt vmcnt(0)\n\ts_barrier" ::: "memory");

  // ---- epilogue: pack + LDS transpose + coalesced dwordx4 stores
  #pragma unroll
  for (int nt = 0; nt < 4; ++nt){
    int nl = wn*64 + nt*16 + 4*quad;     // n base (step 4); rr spans nl..nl+3
    float4 b4;
    if (!brow) b4 = *(const float4*)&bias[bn + nl];
    #pragma unroll
    for (int mt = 0; mt < 4; ++mt){
      int ml = wm*64 + mt*16 + l16;      // m (0..127)
      float bmv = brow ? bias[bm + ml] : 0.0f;
      float v0 = (acc[mt][nt][0] + (brow ? bmv : b4.x)) * scale;
      float v1 = (acc[mt][nt][1] + (brow ? bmv : b4.y)) * scale;
      float v2 = (acc[mt][nt][2] + (brow ? bmv : b4.z)) * scale;
      float v3 = (acc[mt][nt][3] + (brow ? bmv : b4.w)) * scale;
      uint2 p; p.x = pack_bf2(v0, v1); p.y = pack_bf2(v2, v3);
      int gl = nl >> 2;                  // 4-token granule 0..31
      if (brow){                         // fold pi32^-1 (maps 4-runs to 4-runs)
        int g3 = gl & 7;
        gl = (gl & ~7) | ((g3 & 3)*2 + (g3 >> 2));
      }
      int gs = gl ^ (ml & 14);           // even XOR key: write conflicts <=2-way
      *(uint2*)&S[ml*128 + gs*4] = p;
    }
  }
  __syncthreads();
  {
    int rr_ = tid >> 1, hf = tid & 1;    // 2 threads per 128-col row
    size_t rowbase = (size_t)(bm + rr_) * N + bn;
    #pragma unroll
    for (int i = 0; i < 8; ++i){
      int gg = hf*16 + i*2;              // even granule pair
      uint4 d = *(const uint4*)&S[rr_*128 + ((gg ^ (rr_ & 14)) << 2)];
      *(uint4*)&C[rowbase + gg*4] = d;
    }
  }
}

// ---------------------------------------------------------------- out GEMM (fp32)
// (r9 version, unchanged) 64x128 tile, double-buffered BK=64 (48 KB LDS),
// vmcnt(6) + raw barrier skeleton, bijective XCD swizzle, 1D grid 512.
__global__ __launch_bounds__(256) void gemm_out(
    const unsigned short* __restrict__ A, const unsigned short* __restrict__ Bt,
    const float* __restrict__ bias, float* __restrict__ C)
{
  __shared__ __align__(16) unsigned short As[2][64*64];    // 8 KB each
  __shared__ __align__(16) unsigned short Bs[2][128*64];   // 16 KB each
  const int K = 1024, N = 1024;
  const int tid  = threadIdx.x, lane = tid & 63, w = tid >> 6;
  const int quad = lane >> 4,   l16  = lane & 15;
  int bid = blockIdx.x;                                    // XCD swizzle (bijective)
  const int id = (bid & 7) * 64 + (bid >> 3);
  const int bm = (id >> 3) * 64, bn = (id & 7) * 128;
  const int sw = l16 & 7;

  // per-thread staging sources (row&7 granule key, as before)
  const unsigned short* asrc[2];
  const unsigned short* bsrc[4];
  #pragma unroll
  for (int c = 0; c < 2; ++c){               // A: 512 chunks, 2/thread
    int chunk = (w*2 + c)*64 + lane;
    int row = chunk >> 3, c8 = chunk & 7;
    asrc[c] = A + (size_t)(bm + row)*K + ((c8 ^ (row & 7)) << 3);
  }
  #pragma unroll
  for (int c = 0; c < 4; ++c){               // B: 1024 chunks, 4/thread
    int chunk = (w*4 + c)*64 + lane;
    int row = chunk >> 3, c8 = chunk & 7;
    bsrc[c] = Bt + (size_t)(bn + row)*K + ((c8 ^ (row & 7)) << 3);
  }

  // ---- stage k-tile 0 into buf0
  #pragma unroll
  for (int c = 0; c < 2; ++c){ async16(asrc[c], (char*)As[0] + (w*2 + c)*1024); asrc[c] += 64; }
  #pragma unroll
  for (int c = 0; c < 4; ++c){ async16(bsrc[c], (char*)Bs[0] + (w*4 + c)*1024); bsrc[c] += 64; }

  f32x4 acc[4][2] = {};
  for (int t = 0; t < 16; ++t){
    const int cur = t & 1;
    #pragma unroll
    for (int c = 0; c < 2; ++c){            // prefetch tile t+1 (t=15: garbage, in pad)
      async16(asrc[c], (char*)As[1 - cur] + (w*2 + c)*1024); asrc[c] += 64;
    }
    #pragma unroll
    for (int c = 0; c < 4; ++c){
      async16(bsrc[c], (char*)Bs[1 - cur] + (w*4 + c)*1024); bsrc[c] += 64;
    }
    // wait only for CURRENT tile's 6 loads; next tile's 6 stay in flight.
    asm volatile("s_waitcnt vmcnt(6)\n\ts_barrier" ::: "memory");

    const unsigned short* Ac = As[cur];
    bf16x8 af[4][2], bf[2][2];
    #pragma unroll
    for (int mt = 0; mt < 4; ++mt)
      #pragma unroll
      for (int ks = 0; ks < 2; ++ks)
        af[mt][ks] = *(const bf16x8*)&Ac[(mt*16 + l16)*64 + (((ks*4 + quad) ^ sw) << 3)];
    #pragma unroll
    for (int nt = 0; nt < 2; ++nt)
      #pragma unroll
      for (int ks = 0; ks < 2; ++ks)
        bf[nt][ks] = *(const bf16x8*)&Bs[cur][(w*32 + nt*16 + l16)*64 + (((ks*4 + quad) ^ sw) << 3)];
    #pragma unroll
    for (int ks = 0; ks < 2; ++ks)
      #pragma unroll
      for (int mt = 0; mt < 4; ++mt)
        #pragma unroll
        for (int nt = 0; nt < 2; ++nt)
          acc[mt][nt] = mfma16(af[mt][ks], bf[nt][ks], acc[mt][nt]);

    // my frag reads from buf[cur] retired -> safe to restage it next iter.
    asm volatile("s_waitcnt lgkmcnt(0)\n\ts_barrier" ::: "memory");
  }

  #pragma unroll
  for (int mt = 0; mt < 4; ++mt){
    #pragma unroll
    for (int nt = 0; nt < 2; ++nt){
      int col = bn + w*32 + nt*16 + l16;
      float bc = bias[col];
      #pragma unroll
      for (int rr = 0; rr < 4; ++rr){
        int row = bm + mt*16 + quad*4 + rr;
        C[(size_t)row*N + col] = acc[mt][nt][rr] + bc;
      }
    }
  }
}

// ---------------------------------------------------------------- flash attention
// r10: OCCUPANCY via waves, not blocks. grid (SS/128, B*H) unchanged (512
// blocks, 2/CU), but 512 threads = 8 waves x 16 q of the SAME 128-q tile:
// staging per block is unchanged (1 K + 1 V granule per thread, vmcnt(2)),
// so unlike r1's more-blocks attempt nothing is duplicated except LDS
// fragment reads (~30% -> ~60% of LDS pipe, still under the MFMA share).
// 2 blocks x 8 waves = 16 waves/CU (4/SIMD): double the latency-hiding
// against the unchanged serial chain. Per-wave state halves (VGPR ~75).
// P in registers (pi-permuted PV, r3); V as conflict-free b128 (r6).
__global__ __launch_bounds__(512, 4) void attn(
    const unsigned short* __restrict__ Qh, const unsigned short* __restrict__ Kh,
    const unsigned short* __restrict__ Vt, unsigned short* __restrict__ ctx)
{
  __shared__ __align__(16) unsigned short Kbuf[2][64*64];
  __shared__ __align__(16) unsigned short Vbuf[2][64*64];
  __shared__ __align__(16) unsigned short QP[128*64];   // Q tile, then O

  const int tid  = threadIdx.x, lane = tid & 63, w = tid >> 6;   // w: 0..7
  const int quad = lane >> 4,   l16  = lane & 15;
  const int b = blockIdx.y >> 4, h = blockIdx.y & 15;
  const int q0 = blockIdx.x * 128;
  const int sw = l16 & 7;                    // read-side swizzle key (row&7 == l16&7)

  // ---- stage Q tile [128 q][64 dk], swizzled: 1024 granules, 2/thread
  #pragma unroll
  for (int c = 0; c < 2; ++c){
    int s = (w*2 + c)*64 + lane;
    int row = s >> 3, c8 = s & 7;
    async16(Qh + (size_t)(b*SS + q0 + row)*D_MODEL + h*DK + ((c8 ^ (row & 7)) << 3),
            (char*)QP + (w*2 + c)*1024);
  }

  // per-thread staging sources for K and V (1 granule each; bump per stage)
  const unsigned short* Kp = Kh + (size_t)(b*SS)*D_MODEL + h*DK;
  const unsigned short* Vp = Vt + (size_t)(h*DK)*NTOK + b*SS;
  const unsigned short* ksrc;
  const unsigned short* vsrc;
  {
    int s = w*64 + lane;                     // 0..511 granules
    int row = s >> 3, c8 = s & 7;
    int cs = (c8 ^ (row & 7)) << 3;
    ksrc = Kp + (size_t)row*D_MODEL + cs;
    vsrc = Vp + (size_t)row*NTOK  + cs;
  }

  // ---- stage kv tile 0 into buf0
  async16(ksrc, (char*)Kbuf[0] + w*1024);
  async16(vsrc, (char*)Vbuf[0] + w*1024);
  ksrc += 64*D_MODEL;
  vsrc += 64;
  __syncthreads();                           // one-time full drain (Q + tile0)

  bf16x8 bq[2];                              // B-operand = this wave's 16 Q rows
  #pragma unroll
  for (int ks = 0; ks < 2; ++ks)
    bq[ks] = *(const bf16x8*)&QP[(w*16 + l16)*64 + (((ks*4 + quad) ^ sw) << 3)];

  f32x4 acc[4] = {};                         // O^T: [dk-tile], col=q, row=dk
  float l0a = 0.0f, l0b = 0.0f;

  for (int it = 0; it < 32; ++it){
    const int cur = it & 1;
    // prefetch next tile into the other buffer (it=31: garbage prefetch, in-ws)
    async16(ksrc, (char*)Kbuf[1 - cur] + w*1024);
    async16(vsrc, (char*)Vbuf[1 - cur] + w*1024);
    ksrc += 64*D_MODEL;
    vsrc += 64;
    // wait only for CURRENT tile's 2 loads (issued a full compute phase ago);
    // next tile's 2 stay in flight. Raw barrier: no vmcnt(0) drain.
    asm volatile("s_waitcnt vmcnt(2)\n\ts_barrier" ::: "memory");

    const unsigned short* Kc = Kbuf[cur];
    const unsigned short* Vc = Vbuf[cur];

    // K fragments (full 64 kv rows)
    bf16x8 kf[4][2];
    #pragma unroll
    for (int mt = 0; mt < 4; ++mt)
      #pragma unroll
      for (int ks = 0; ks < 2; ++ks)
        kf[mt][ks] = *(const bf16x8*)&Kc[(mt*16 + l16)*64 + (((ks*4 + quad) ^ sw) << 3)];

    // V fragments: contiguous b128, conflict-free (Vt pre-permuted by pi32^-1)
    bf16x8 vf[4][2];
    #pragma unroll
    for (int nt = 0; nt < 4; ++nt)
      #pragma unroll
      for (int ks = 0; ks < 2; ++ks)
        vf[nt][ks] = *(const bf16x8*)&Vc[(nt*16 + l16)*64 + (((ks*4 + quad) ^ sw) << 3)];

    // S^T = K.Q^T for this wave's 16 q
    f32x4 s0[4] = {};
    #pragma unroll
    for (int mt = 0; mt < 4; ++mt)
      #pragma unroll
      for (int ks = 0; ks < 2; ++ks)
        s0[mt] = mfma16(kf[mt][ks], bq[ks], s0[mt]);

    // softmax (no max subtraction), two partial sums
    float sa = 0.0f, sb = 0.0f;
    #pragma unroll
    for (int mt = 0; mt < 4; ++mt)
      #pragma unroll
      for (int rr = 0; rr < 4; ++rr){
        float p0 = fast_exp2(s0[mt][rr]); s0[mt][rr] = p0;
        if (mt & 1) sb += p0; else sa += p0;
      }
    l0a += sa; l0b += sb;

    // in-register P -> bf16 B-fragments (natural register order under pi)
    bf16x8 bp[2];
    #pragma unroll
    for (int ks = 0; ks < 2; ++ks){
      uint4 t;
      t.x = cvt_pk_bf16(s0[2*ks  ][0], s0[2*ks  ][1]);
      t.y = cvt_pk_bf16(s0[2*ks  ][2], s0[2*ks  ][3]);
      t.z = cvt_pk_bf16(s0[2*ks+1][0], s0[2*ks+1][1]);
      t.w = cvt_pk_bf16(s0[2*ks+1][2], s0[2*ks+1][3]);
      bp[ks] = __builtin_bit_cast(bf16x8, t);
    }

    // O^T += V^T.P^T (k-permuted on both sides)
    #pragma unroll
    for (int nt = 0; nt < 4; ++nt)
      #pragma unroll
      for (int ks = 0; ks < 2; ++ks)
        acc[nt] = mfma16(vf[nt][ks], bp[ks], acc[nt]);

    // all my LDS reads from buf[cur] retired -> safe for others to restage it.
    // Raw barrier: prefetch (vmcnt) stays in flight.
    asm volatile("s_waitcnt lgkmcnt(0)\n\ts_barrier" ::: "memory");
  }

  // ---- epilogue: normalize, O^T -> QP (wave-private rows), transpose out
  float t = l0a + l0b;
  t += __shfl_xor(t, 16);
  t += __shfl_xor(t, 32);
  const float inv = 1.0f / t;

  {
    const int pr = (w*16 + l16)*64;
    #pragma unroll
    for (int nt = 0; nt < 4; ++nt){
      int c8  = nt*2 + (quad >> 1);
      int off = ((c8 ^ sw) << 3) + (quad & 1)*4;
      uint2 p;
      p.x = pack_bf2(acc[nt][0]*inv, acc[nt][1]*inv);
      p.y = pack_bf2(acc[nt][2]*inv, acc[nt][3]*inv);
      *(uint2*)&QP[pr + off] = p;
    }
  }
  asm volatile("s_waitcnt lgkmcnt(0)" ::: "memory");
  {
    int r  = w*16 + (lane >> 2);             // wave-private rows: no barrier needed
    int j0 = lane & 3;
    unsigned short* dst = ctx + (size_t)(b*SS + q0 + r)*D_MODEL + h*DK;
    #pragma unroll
    for (int i = 0; i < 2; ++i){
      int j = j0 + i*4;
      uint4 d = *(const uint4*)&QP[r*64 + ((j ^ (r & 7)) << 3)];
      *(uint4*)(dst + j*8) = d;
    }
  }
}

// ---------------------------------------------------------------- launch
extern "C" void kernel_launch(void* const* d_in, const int* in_sizes, int n_in,
                              void* d_out, int out_size, void* d_ws, size_t ws_size,
                              hipStream_t stream) {
  const float* q  = (const float*)d_in[0];
  const float* k  = (const float*)d_in[1];
  const float* v  = (const float*)d_in[2];
  const float* Wq = (const float*)d_in[3];
  const float* bq = (const float*)d_in[4];
  const float* Wk = (const float*)d_in[5];
  const float* bk = (const float*)d_in[6];
  const float* Wv = (const float*)d_in[7];
  const float* bv = (const float*)d_in[8];
  const float* Wo = (const float*)d_in[9];
  const float* bo = (const float*)d_in[10];

  char* ws = (char*)d_ws;
  const size_t TOKB = (size_t)NTOK * D_MODEL * 2;     // 8 MB
  const size_t WB   = (size_t)D_MODEL * D_MODEL * 2;  // 2 MB
  unsigned short* qb  = (unsigned short*)ws;             ws += TOKB;
  unsigned short* kb  = (unsigned short*)ws;             ws += TOKB;
  unsigned short* vb  = (unsigned short*)ws;             ws += TOKB;
  unsigned short* wqb = (unsigned short*)ws;             ws += WB;
  unsigned short* wkb = (unsigned short*)ws;             ws += WB;
  unsigned short* wvb = (unsigned short*)ws;             ws += WB;
  unsigned short* wob = (unsigned short*)ws;             ws += WB;
  unsigned short* Qh  = (unsigned short*)ws;             ws += TOKB;  // [4096][1024], pre-scaled
  unsigned short* Kh  = (unsigned short*)ws;             ws += TOKB;  // [4096][1024]
  unsigned short* Vt  = (unsigned short*)ws;             ws += TOKB;  // [1024][4096], pi-permuted cols
  unsigned short* ctx = (unsigned short*)ws;             ws += TOKB;  // [4096][1024]
  ws += 4096;   // pad: gemm_out's t=15 garbage prefetch reads <=128B past ctx

  cast_bf16_all<<<dim3(2048, 7), 256, 0, stream>>>(q, k, v, Wq, Wk, Wv, Wo,
                                                   qb, kb, vb, wqb, wkb, wvb, wob);
  qkv_gemm<<<dim3(768), 256, 0, stream>>>(qb, kb, vb, wqb, wkb, wvb,
                                          bq, bk, bv, Qh, Kh, Vt);
  attn<<<dim3(SS/128, BB*NHEAD), 512, 0, stream>>>(Qh, Kh, Vt, ctx);
  gemm_out<<<dim3(512), 256, 0, stream>>>(ctx, wob, bo, (float*)d_out);
}

// Round 11
// 211.675 us; speedup vs baseline: 1.1494x; 1.0048x over previous
//
#include <hip/hip_runtime.h>
#include <stdint.h>
#include <stddef.h>

#define D_MODEL 1024
#define NHEAD   16
#define DK      64
#define BB      2
#define SS      2048
#define NTOK    (BB*SS)   // 4096

// log2(e) / sqrt(Dk) folded into the Q projection output:
#define SCALE_Q 0.18033688011f

typedef short  short8 __attribute__((ext_vector_type(8)));
typedef __bf16 bf16x8 __attribute__((ext_vector_type(8)));
typedef float  f32x4  __attribute__((ext_vector_type(4)));

__device__ __forceinline__ unsigned short f2bf(float x){   // RNE (cast path)
  unsigned int u = __builtin_bit_cast(unsigned int, x);
  u += 0x7fffu + ((u >> 16) & 1u);
  return (unsigned short)(u >> 16);
}

// pack two f32 -> two bf16 (round-half-up) in 3 VALU: add, add, v_perm
__device__ __forceinline__ unsigned int pack_bf2(float x, float y){
  unsigned int a = __builtin_bit_cast(unsigned int, x) + 0x8000u;
  unsigned int b = __builtin_bit_cast(unsigned int, y) + 0x8000u;
  return __builtin_amdgcn_perm(b, a, 0x07060302u);  // [y_hi16 | x_hi16]
}

// two f32 -> packed bf16x2 in ONE VALU (RNE). dst.lo = lo, dst.hi = hi.
__device__ __forceinline__ unsigned int cvt_pk_bf16(float lo, float hi){
  unsigned int r;
  asm("v_cvt_pk_bf16_f32 %0, %1, %2" : "=v"(r) : "v"(lo), "v"(hi));
  return r;
}

__device__ __forceinline__ float fast_exp2(float x){
#if __has_builtin(__builtin_amdgcn_exp2f)
  return __builtin_amdgcn_exp2f(x);   // raw v_exp_f32; args bounded, no denorms
#else
  return exp2f(x);
#endif
}

__device__ __forceinline__ f32x4 mfma16(bf16x8 a, bf16x8 b, f32x4 c){
  return __builtin_amdgcn_mfma_f32_16x16x32_bf16(a, b, c, 0, 0, 0);
}

// async global->LDS, 16B/lane; LDS dst = wave-uniform base + lane*16
__device__ __forceinline__ void async16(const void* g, void* lds){
  __builtin_amdgcn_global_load_lds(
      (const __attribute__((address_space(1))) unsigned int*)g,
      (__attribute__((address_space(3))) unsigned int*)lds,
      16, 0, 0);
}

// ---------------------------------------------------------------- cast fp32->bf16
__global__ __launch_bounds__(256) void cast_bf16_all(
    const float* __restrict__ q,  const float* __restrict__ k,  const float* __restrict__ v,
    const float* __restrict__ wq, const float* __restrict__ wk, const float* __restrict__ wv,
    const float* __restrict__ wo,
    unsigned short* __restrict__ qb,  unsigned short* __restrict__ kb,  unsigned short* __restrict__ vb,
    unsigned short* __restrict__ wqb, unsigned short* __restrict__ wkb, unsigned short* __restrict__ wvb,
    unsigned short* __restrict__ wob)
{
  const float* src; unsigned short* dst; int n;
  switch (blockIdx.y){
    case 0: src = q;  dst = qb;  n = NTOK*D_MODEL;    break;
    case 1: src = k;  dst = kb;  n = NTOK*D_MODEL;    break;
    case 2: src = v;  dst = vb;  n = NTOK*D_MODEL;    break;
    case 3: src = wq; dst = wqb; n = D_MODEL*D_MODEL; break;
    case 4: src = wk; dst = wkb; n = D_MODEL*D_MODEL; break;
    case 5: src = wv; dst = wvb; n = D_MODEL*D_MODEL; break;
    default: src = wo; dst = wob; n = D_MODEL*D_MODEL; break;
  }
  int i = (blockIdx.x * 256 + threadIdx.x) * 8;
  if (i >= n) return;
  float4 a = *(const float4*)(src + i);
  float4 b = *(const float4*)(src + i + 4);
  short8 o;
  o[0] = (short)f2bf(a.x); o[1] = (short)f2bf(a.y);
  o[2] = (short)f2bf(a.z); o[3] = (short)f2bf(a.w);
  o[4] = (short)f2bf(b.x); o[5] = (short)f2bf(b.y);
  o[6] = (short)f2bf(b.z); o[7] = (short)f2bf(b.w);
  *(short8*)(dst + i) = o;
}

// ---------------------------------------------------------------- fused QKV NT GEMM
// (r8 version, unchanged) z=0: Qh=(qb.Wq^T+bq)*SCALE_Q; z=1: Kh=kb.Wk^T+bk;
// z=2: Vt=Wv.vb^T+bv. 128x128 tile, DOUBLE-BUFFERED BK=32 K-loop in 32 KB LDS:
// issue stage(t+1) -> vmcnt(4) + raw s_barrier -> 8 ds_read_b128 -> 16 MFMA ->
// lgkmcnt(0) + raw s_barrier. Bijective XCD swizzle. r7 epilogue (swapped
// operands + LDS transpose + coalesced stores; z=2 folds pi32^-1).
__global__ __launch_bounds__(256) void qkv_gemm(
    const unsigned short* __restrict__ qb, const unsigned short* __restrict__ kb,
    const unsigned short* __restrict__ vb,
    const unsigned short* __restrict__ wqb, const unsigned short* __restrict__ wkb,
    const unsigned short* __restrict__ wvb,
    const float* __restrict__ bq, const float* __restrict__ bk, const float* __restrict__ bv,
    unsigned short* __restrict__ Qh, unsigned short* __restrict__ Kh, unsigned short* __restrict__ Vt)
{
  __shared__ __align__(16) unsigned short S[128*128];   // 32 KB total
  unsigned short* As0 = S;                              // [128 m][32 k] 8 KB
  unsigned short* Bs0 = S + 4096;
  unsigned short* As1 = S + 8192;
  unsigned short* Bs1 = S + 12288;

  int bid = blockIdx.x;                                 // XCD swizzle (bijective)
  const int id = (bid & 7) * 96 + (bid >> 3);
  const int z = id >> 8, r = id & 255;
  const unsigned short *A, *Bt; const float* bias; unsigned short* C;
  int bm, bn, N, brow; float scale;
  if (z == 0){ A = qb;  Bt = wqb; bias = bq; C = Qh; bm = (r>>3)*128; bn = (r&7)*128; N = 1024; brow = 0; scale = SCALE_Q; }
  else if (z == 1){ A = kb;  Bt = wkb; bias = bk; C = Kh; bm = (r>>3)*128; bn = (r&7)*128; N = 1024; brow = 0; scale = 1.0f; }
  else            { A = wvb; Bt = vb;  bias = bv; C = Vt; bm = (r&7)*128; bn = (r>>3)*128; N = 4096; brow = 1; scale = 1.0f; }
  const int K = 1024;
  const int tid  = threadIdx.x, lane = tid & 63, w = tid >> 6;
  const int quad = lane >> 4,   l16  = lane & 15;
  const int wm = w >> 1, wn = w & 1;
  const int fsl = (quad ^ ((l16 >> 2) & 3)) << 3;       // fragment-read elem offset

  // per-thread staging sources (BK=32 tile: 512 granules, 2/thread each side)
  const unsigned short* asrc[2];
  const unsigned short* bsrc[2];
  #pragma unroll
  for (int c = 0; c < 2; ++c){
    int s = (w*2 + c)*64 + lane;
    int row = s >> 2, c4 = s & 3;
    int cs = (c4 ^ ((row >> 2) & 3)) << 3;
    asrc[c] = A  + (size_t)(bm + row)*K + cs;
    bsrc[c] = Bt + (size_t)(bn + row)*K + cs;
  }

  // ---- stage k-tile 0 into buf0
  #pragma unroll
  for (int c = 0; c < 2; ++c){
    async16(asrc[c], (char*)As0 + (w*2 + c)*1024);
    async16(bsrc[c], (char*)Bs0 + (w*2 + c)*1024);
    asrc[c] += 32; bsrc[c] += 32;
  }

  f32x4 acc[4][4] = {};
  for (int t = 0; t < 32; ++t){
    const int cur = t & 1;
    unsigned short* An = cur ? As0 : As1;   // next buffer
    unsigned short* Bn = cur ? Bs0 : Bs1;
    #pragma unroll
    for (int c = 0; c < 2; ++c){            // prefetch tile t+1 (t=31: garbage, in-ws)
      async16(asrc[c], (char*)An + (w*2 + c)*1024);
      async16(bsrc[c], (char*)Bn + (w*2 + c)*1024);
      asrc[c] += 32; bsrc[c] += 32;
    }
    // wait only for CURRENT tile's 4 loads; next tile's 4 stay in flight.
    asm volatile("s_waitcnt vmcnt(4)\n\ts_barrier" ::: "memory");

    const unsigned short* Ac = cur ? As1 : As0;
    const unsigned short* Bc = cur ? Bs1 : Bs0;
    bf16x8 af[4], bf[4];
    #pragma unroll
    for (int mt = 0; mt < 4; ++mt){
      af[mt] = *(const bf16x8*)&Ac[(wm*64 + mt*16 + l16)*32 + fsl];
      bf[mt] = *(const bf16x8*)&Bc[(wn*64 + mt*16 + l16)*32 + fsl];
    }
    // SWAPPED operand order: output col = l16 = m, rows = n (4quad+rr).
    #pragma unroll
    for (int mt = 0; mt < 4; ++mt)
      #pragma unroll
      for (int nt = 0; nt < 4; ++nt)
        acc[mt][nt] = mfma16(bf[nt], af[mt], acc[mt][nt]);

    // my frag reads from buf[cur] retired -> safe to restage it next iter.
    asm volatile("s_waitcnt lgkmcnt(0)\n\ts_barrier" ::: "memory");
  }
  // garbage tile-32 DMA may still target As0/Bs0 (= S): drain before reuse.
  asm volatile("s_waitcnt vmcnt(0)\n\ts_barrier" ::: "memory");

  // ---- epilogue: pack + LDS transpose + coalesced dwordx4 stores
  #pragma unroll
  for (int nt = 0; nt < 4; ++nt){
    int nl = wn*64 + nt*16 + 4*quad;     // n base (step 4); rr spans nl..nl+3
    float4 b4;
    if (!brow) b4 = *(const float4*)&bias[bn + nl];
    #pragma unroll
    for (int mt = 0; mt < 4; ++mt){
      int ml = wm*64 + mt*16 + l16;      // m (0..127)
      float bmv = brow ? bias[bm + ml] : 0.0f;
      float v0 = (acc[mt][nt][0] + (brow ? bmv : b4.x)) * scale;
      float v1 = (acc[mt][nt][1] + (brow ? bmv : b4.y)) * scale;
      float v2 = (acc[mt][nt][2] + (brow ? bmv : b4.z)) * scale;
      float v3 = (acc[mt][nt][3] + (brow ? bmv : b4.w)) * scale;
      uint2 p; p.x = pack_bf2(v0, v1); p.y = pack_bf2(v2, v3);
      int gl = nl >> 2;                  // 4-token granule 0..31
      if (brow){                         // fold pi32^-1 (maps 4-runs to 4-runs)
        int g3 = gl & 7;
        gl = (gl & ~7) | ((g3 & 3)*2 + (g3 >> 2));
      }
      int gs = gl ^ (ml & 14);           // even XOR key: write conflicts <=2-way
      *(uint2*)&S[ml*128 + gs*4] = p;
    }
  }
  __syncthreads();
  {
    int rr_ = tid >> 1, hf = tid & 1;    // 2 threads per 128-col row
    size_t rowbase = (size_t)(bm + rr_) * N + bn;
    #pragma unroll
    for (int i = 0; i < 8; ++i){
      int gg = hf*16 + i*2;              // even granule pair
      uint4 d = *(const uint4*)&S[rr_*128 + ((gg ^ (rr_ & 14)) << 2)];
      *(uint4*)&C[rowbase + gg*4] = d;
    }
  }
}

// ---------------------------------------------------------------- out GEMM (fp32)
// (r9 version, unchanged) 64x128 tile, double-buffered BK=64 (48 KB LDS),
// vmcnt(6) + raw barrier skeleton, bijective XCD swizzle, 1D grid 512.
__global__ __launch_bounds__(256) void gemm_out(
    const unsigned short* __restrict__ A, const unsigned short* __restrict__ Bt,
    const float* __restrict__ bias, float* __restrict__ C)
{
  __shared__ __align__(16) unsigned short As[2][64*64];    // 8 KB each
  __shared__ __align__(16) unsigned short Bs[2][128*64];   // 16 KB each
  const int K = 1024, N = 1024;
  const int tid  = threadIdx.x, lane = tid & 63, w = tid >> 6;
  const int quad = lane >> 4,   l16  = lane & 15;
  int bid = blockIdx.x;                                    // XCD swizzle (bijective)
  const int id = (bid & 7) * 64 + (bid >> 3);
  const int bm = (id >> 3) * 64, bn = (id & 7) * 128;
  const int sw = l16 & 7;

  // per-thread staging sources (row&7 granule key, as before)
  const unsigned short* asrc[2];
  const unsigned short* bsrc[4];
  #pragma unroll
  for (int c = 0; c < 2; ++c){               // A: 512 chunks, 2/thread
    int chunk = (w*2 + c)*64 + lane;
    int row = chunk >> 3, c8 = chunk & 7;
    asrc[c] = A + (size_t)(bm + row)*K + ((c8 ^ (row & 7)) << 3);
  }
  #pragma unroll
  for (int c = 0; c < 4; ++c){               // B: 1024 chunks, 4/thread
    int chunk = (w*4 + c)*64 + lane;
    int row = chunk >> 3, c8 = chunk & 7;
    bsrc[c] = Bt + (size_t)(bn + row)*K + ((c8 ^ (row & 7)) << 3);
  }

  // ---- stage k-tile 0 into buf0
  #pragma unroll
  for (int c = 0; c < 2; ++c){ async16(asrc[c], (char*)As[0] + (w*2 + c)*1024); asrc[c] += 64; }
  #pragma unroll
  for (int c = 0; c < 4; ++c){ async16(bsrc[c], (char*)Bs[0] + (w*4 + c)*1024); bsrc[c] += 64; }

  f32x4 acc[4][2] = {};
  for (int t = 0; t < 16; ++t){
    const int cur = t & 1;
    #pragma unroll
    for (int c = 0; c < 2; ++c){            // prefetch tile t+1 (t=15: garbage, in pad)
      async16(asrc[c], (char*)As[1 - cur] + (w*2 + c)*1024); asrc[c] += 64;
    }
    #pragma unroll
    for (int c = 0; c < 4; ++c){
      async16(bsrc[c], (char*)Bs[1 - cur] + (w*4 + c)*1024); bsrc[c] += 64;
    }
    // wait only for CURRENT tile's 6 loads; next tile's 6 stay in flight.
    asm volatile("s_waitcnt vmcnt(6)\n\ts_barrier" ::: "memory");

    const unsigned short* Ac = As[cur];
    bf16x8 af[4][2], bf[2][2];
    #pragma unroll
    for (int mt = 0; mt < 4; ++mt)
      #pragma unroll
      for (int ks = 0; ks < 2; ++ks)
        af[mt][ks] = *(const bf16x8*)&Ac[(mt*16 + l16)*64 + (((ks*4 + quad) ^ sw) << 3)];
    #pragma unroll
    for (int nt = 0; nt < 2; ++nt)
      #pragma unroll
      for (int ks = 0; ks < 2; ++ks)
        bf[nt][ks] = *(const bf16x8*)&Bs[cur][(w*32 + nt*16 + l16)*64 + (((ks*4 + quad) ^ sw) << 3)];
    #pragma unroll
    for (int ks = 0; ks < 2; ++ks)
      #pragma unroll
      for (int mt = 0; mt < 4; ++mt)
        #pragma unroll
        for (int nt = 0; nt < 2; ++nt)
          acc[mt][nt] = mfma16(af[mt][ks], bf[nt][ks], acc[mt][nt]);

    // my frag reads from buf[cur] retired -> safe to restage it next iter.
    asm volatile("s_waitcnt lgkmcnt(0)\n\ts_barrier" ::: "memory");
  }

  #pragma unroll
  for (int mt = 0; mt < 4; ++mt){
    #pragma unroll
    for (int nt = 0; nt < 2; ++nt){
      int col = bn + w*32 + nt*16 + l16;
      float bc = bias[col];
      #pragma unroll
      for (int rr = 0; rr < 4; ++rr){
        int row = bm + mt*16 + quad*4 + rr;
        C[(size_t)row*N + col] = acc[mt][nt][rr] + bc;
      }
    }
  }
}

// ---------------------------------------------------------------- flash attention
// r11: KV-SPLIT WAVES to halve LDS fragment traffic (r10's measured wall:
// 256 ds_read_b128/round x 12cyc = 89% of the 3456-cyc round).
// 512 threads = 8 waves; pair p = w>>1 owns q rows p*32..p*32+31; hk = w&1
// owns one 32-kv half. Per wave-iter: 4 K-frag + 4 V-frag b128 reads (was 16),
// 8 QK + 8 PV MFMA (total MFMA/exp/cvt unchanged). No-max softmax is additive
// over kv, so the two halves accumulate independently for all 32 iterations
// and merge ONCE in the epilogue: B(hk=1) writes f32 O-partials into the
// retired K/V LDS buffers (drained via vmcnt(0)) + l halves into lbuf;
// A(hk=0) merges, normalizes, stages to QP, transpose-out.
// P in registers (pi-permuted PV, r3); V as conflict-free b128 (r6).
__global__ __launch_bounds__(512, 4) void attn(
    const unsigned short* __restrict__ Qh, const unsigned short* __restrict__ Kh,
    const unsigned short* __restrict__ Vt, unsigned short* __restrict__ ctx)
{
  __shared__ __align__(16) unsigned short SH[24576];   // 48 KB
  unsigned short* Kb = SH;                             // K tiles: 2 x 4096 shorts
  unsigned short* Vb = SH + 8192;                      // V tiles: 2 x 4096 shorts
  unsigned short* QP = SH + 16384;                     // [128 q][64 dk]
  __shared__ float lbuf[256];                          // l halves: [pair][hk][32 q]

  const int tid  = threadIdx.x, lane = tid & 63, w = tid >> 6;   // w: 0..7
  const int quad = lane >> 4,   l16  = lane & 15;
  const int p = w >> 1, hk = w & 1;
  const int b = blockIdx.y >> 4, h = blockIdx.y & 15;
  const int q0 = blockIdx.x * 128;
  const int sw = l16 & 7;                    // read-side swizzle key (row&7 == l16&7)

  // ---- stage Q tile [128 q][64 dk], swizzled: 1024 granules, 2/thread
  #pragma unroll
  for (int c = 0; c < 2; ++c){
    int s = (w*2 + c)*64 + lane;
    int row = s >> 3, c8 = s & 7;
    async16(Qh + (size_t)(b*SS + q0 + row)*D_MODEL + h*DK + ((c8 ^ (row & 7)) << 3),
            (char*)QP + (w*2 + c)*1024);
  }

  // per-thread staging sources for K and V (1 granule each; bump per stage)
  const unsigned short* Kp = Qh; // placeholder to keep types; real init below
  (void)Kp;
  const unsigned short* ksrc;
  const unsigned short* vsrc;
  {
    const unsigned short* Kpp = Kh + (size_t)(b*SS)*D_MODEL + h*DK;
    const unsigned short* Vpp = Vt + (size_t)(h*DK)*NTOK + b*SS;
    int s = w*64 + lane;                     // 0..511 granules
    int row = s >> 3, c8 = s & 7;
    int cs = (c8 ^ (row & 7)) << 3;
    ksrc = Kpp + (size_t)row*D_MODEL + cs;
    vsrc = Vpp + (size_t)row*NTOK  + cs;
  }

  // ---- stage kv tile 0 into buf0
  async16(ksrc, (char*)Kb + w*1024);
  async16(vsrc, (char*)Vb + w*1024);
  ksrc += 64*D_MODEL;
  vsrc += 64;
  __syncthreads();                           // one-time full drain (Q + tile0)

  bf16x8 bq[2][2];                           // [nq][ks]: this pair's 32 Q rows
  #pragma unroll
  for (int nq = 0; nq < 2; ++nq)
    #pragma unroll
    for (int ks = 0; ks < 2; ++ks)
      bq[nq][ks] = *(const bf16x8*)&QP[(p*32 + nq*16 + l16)*64 + (((ks*4 + quad) ^ sw) << 3)];

  f32x4 acc[4][2] = {};                      // O^T partial: [nt dk-tile][nq]
  float l0 = 0.0f, l1 = 0.0f;                // l partials per nq

  for (int it = 0; it < 32; ++it){
    const int cur = it & 1;
    // prefetch next tile into the other buffer (it=31: garbage prefetch, in-ws)
    async16(ksrc, (char*)(Kb + (1 - cur)*4096) + w*1024);
    async16(vsrc, (char*)(Vb + (1 - cur)*4096) + w*1024);
    ksrc += 64*D_MODEL;
    vsrc += 64;
    // wait only for CURRENT tile's 2 loads; next tile's 2 stay in flight.
    asm volatile("s_waitcnt vmcnt(2)\n\ts_barrier" ::: "memory");

    const unsigned short* Kc = Kb + cur*4096;
    const unsigned short* Vc = Vb + cur*4096;

    // K fragments: this wave's 32 kv rows only (2 mt x 2 ks = 4 b128)
    bf16x8 kf[2][2];
    #pragma unroll
    for (int mt = 0; mt < 2; ++mt)
      #pragma unroll
      for (int ks = 0; ks < 2; ++ks)
        kf[mt][ks] = *(const bf16x8*)&Kc[(hk*32 + mt*16 + l16)*64 + (((ks*4 + quad) ^ sw) << 3)];

    // V fragments: this wave's kv half only (4 nt = 4 b128), pi-permuted layout
    bf16x8 vf[4];
    #pragma unroll
    for (int nt = 0; nt < 4; ++nt)
      vf[nt] = *(const bf16x8*)&Vc[(nt*16 + l16)*64 + (((hk*4 + quad) ^ sw) << 3)];

    // S^T = K.Q^T for 32 kv x 32 q
    f32x4 s0[2][2] = {};                     // [mt][nq]
    #pragma unroll
    for (int mt = 0; mt < 2; ++mt)
      #pragma unroll
      for (int ks = 0; ks < 2; ++ks){
        s0[mt][0] = mfma16(kf[mt][ks], bq[0][ks], s0[mt][0]);
        s0[mt][1] = mfma16(kf[mt][ks], bq[1][ks], s0[mt][1]);
      }

    // softmax (no max subtraction)
    float sa = 0.0f, sb = 0.0f;
    #pragma unroll
    for (int mt = 0; mt < 2; ++mt)
      #pragma unroll
      for (int rr = 0; rr < 4; ++rr){
        float v0 = fast_exp2(s0[mt][0][rr]); s0[mt][0][rr] = v0; sa += v0;
        float v1 = fast_exp2(s0[mt][1][rr]); s0[mt][1][rr] = v1; sb += v1;
      }
    l0 += sa; l1 += sb;

    // in-register P -> bf16 B-fragments (natural register order under pi;
    // local mt 0,1 are global kv tiles 2hk, 2hk+1 — matches the vf offset)
    bf16x8 bp[2];
    #pragma unroll
    for (int nq = 0; nq < 2; ++nq){
      uint4 t;
      t.x = cvt_pk_bf16(s0[0][nq][0], s0[0][nq][1]);
      t.y = cvt_pk_bf16(s0[0][nq][2], s0[0][nq][3]);
      t.z = cvt_pk_bf16(s0[1][nq][0], s0[1][nq][1]);
      t.w = cvt_pk_bf16(s0[1][nq][2], s0[1][nq][3]);
      bp[nq] = __builtin_bit_cast(bf16x8, t);
    }

    // O^T partial += V^T.P^T over this kv half
    #pragma unroll
    for (int nt = 0; nt < 4; ++nt)
      #pragma unroll
      for (int nq = 0; nq < 2; ++nq)
        acc[nt][nq] = mfma16(vf[nt], bp[nq], acc[nt][nq]);

    // all my LDS reads from buf[cur] retired -> safe for others to restage it.
    asm volatile("s_waitcnt lgkmcnt(0)\n\ts_barrier" ::: "memory");
  }

  // ---- epilogue: merge kv halves, normalize, stage to QP, transpose out
  // drain the it=31 garbage DMA targeting Kb/Vb, then reuse that 32KB as f32
  // merge scratch.
  asm volatile("s_waitcnt vmcnt(0)\n\ts_barrier" ::: "memory");

  float t0 = l0; t0 += __shfl_xor(t0, 16); t0 += __shfl_xor(t0, 32);
  float t1 = l1; t1 += __shfl_xor(t1, 16); t1 += __shfl_xor(t1, 32);
  if (quad == 0){
    lbuf[(p*2 + hk)*32 +      l16] = t0;
    lbuf[(p*2 + hk)*32 + 16 + l16] = t1;
  }
  float* OS = (float*)SH;                    // [pair][32 q][64 dk] f32, 32 KB
  if (hk){
    #pragma unroll
    for (int nt = 0; nt < 4; ++nt)
      #pragma unroll
      for (int nq = 0; nq < 2; ++nq){
        int qq = nq*16 + l16;
        int d0 = (nt*16 + quad*4) ^ ((qq & 7) << 2);   // XOR: ~2 lanes/bank
        *(f32x4*)&OS[p*2048 + qq*64 + d0] = acc[nt][nq];
      }
  }
  __syncthreads();
  if (!hk){
    float inv0 = 1.0f / (t0 + lbuf[(p*2 + 1)*32 +      l16]);
    float inv1 = 1.0f / (t1 + lbuf[(p*2 + 1)*32 + 16 + l16]);
    #pragma unroll
    for (int nq = 0; nq < 2; ++nq){
      float inv = nq ? inv1 : inv0;
      int qq = nq*16 + l16;
      int pr = (p*32 + qq)*64;
      #pragma unroll
      for (int nt = 0; nt < 4; ++nt){
        int d0 = (nt*16 + quad*4) ^ ((qq & 7) << 2);
        f32x4 ob = *(const f32x4*)&OS[p*2048 + qq*64 + d0];
        float v0 = (acc[nt][nq][0] + ob[0]) * inv;
        float v1 = (acc[nt][nq][1] + ob[1]) * inv;
        float v2 = (acc[nt][nq][2] + ob[2]) * inv;
        float v3 = (acc[nt][nq][3] + ob[3]) * inv;
        int c8  = nt*2 + (quad >> 1);
        int off = ((c8 ^ sw) << 3) + (quad & 1)*4;
        uint2 pk;
        pk.x = pack_bf2(v0, v1);
        pk.y = pack_bf2(v2, v3);
        *(uint2*)&QP[pr + off] = pk;
      }
    }
    asm volatile("s_waitcnt lgkmcnt(0)" ::: "memory");
    // transpose out: A wave p covers rows p*32..p*32+31 (wave-private)
    int r  = p*32 + (lane >> 1);
    int j0 = (lane & 1)*4;
    unsigned short* dst = ctx + (size_t)(b*SS + q0 + r)*D_MODEL + h*DK;
    #pragma unroll
    for (int i = 0; i < 4; ++i){
      int j = j0 + i;
      uint4 d = *(const uint4*)&QP[r*64 + ((j ^ (r & 7)) << 3)];
      *(uint4*)(dst + j*8) = d;
    }
  }
}

// ---------------------------------------------------------------- launch
extern "C" void kernel_launch(void* const* d_in, const int* in_sizes, int n_in,
                              void* d_out, int out_size, void* d_ws, size_t ws_size,
                              hipStream_t stream) {
  const float* q  = (const float*)d_in[0];
  const float* k  = (const float*)d_in[1];
  const float* v  = (const float*)d_in[2];
  const float* Wq = (const float*)d_in[3];
  const float* bq = (const float*)d_in[4];
  const float* Wk = (const float*)d_in[5];
  const float* bk = (const float*)d_in[6];
  const float* Wv = (const float*)d_in[7];
  const float* bv = (const float*)d_in[8];
  const float* Wo = (const float*)d_in[9];
  const float* bo = (const float*)d_in[10];

  char* ws = (char*)d_ws;
  const size_t TOKB = (size_t)NTOK * D_MODEL * 2;     // 8 MB
  const size_t WB   = (size_t)D_MODEL * D_MODEL * 2;  // 2 MB
  unsigned short* qb  = (unsigned short*)ws;             ws += TOKB;
  unsigned short* kb  = (unsigned short*)ws;             ws += TOKB;
  unsigned short* vb  = (unsigned short*)ws;             ws += TOKB;
  unsigned short* wqb = (unsigned short*)ws;             ws += WB;
  unsigned short* wkb = (unsigned short*)ws;             ws += WB;
  unsigned short* wvb = (unsigned short*)ws;             ws += WB;
  unsigned short* wob = (unsigned short*)ws;             ws += WB;
  unsigned short* Qh  = (unsigned short*)ws;             ws += TOKB;  // [4096][1024], pre-scaled
  unsigned short* Kh  = (unsigned short*)ws;             ws += TOKB;  // [4096][1024]
  unsigned short* Vt  = (unsigned short*)ws;             ws += TOKB;  // [1024][4096], pi-permuted cols
  unsigned short* ctx = (unsigned short*)ws;             ws += TOKB;  // [4096][1024]
  ws += 4096;   // pad: gemm_out's t=15 garbage prefetch reads <=128B past ctx

  cast_bf16_all<<<dim3(2048, 7), 256, 0, stream>>>(q, k, v, Wq, Wk, Wv, Wo,
                                                   qb, kb, vb, wqb, wkb, wvb, wob);
  qkv_gemm<<<dim3(768), 256, 0, stream>>>(qb, kb, vb, wqb, wkb, wvb,
                                          bq, bk, bv, Qh, Kh, Vt);
  attn<<<dim3(SS/128, BB*NHEAD), 512, 0, stream>>>(Qh, Kh, Vt, ctx);
  gemm_out<<<dim3(512), 256, 0, stream>>>(ctx, wob, bo, (float*)d_out);
}